// Round 10
// baseline (460.605 us; speedup 1.0000x reference)
//
#include <hip/hip_runtime.h>

// Problem constants
constexpr int kB  = 4;
constexpr int kT  = 16;
constexpr int kN  = 4096;
constexpr int kBN = kB * kN;      // 16384
constexpr int kE  = 32768;
constexpr int kNC = 13;

typedef _Float16 f16x8 __attribute__((ext_vector_type(8)));
typedef _Float16 f16x4 __attribute__((ext_vector_type(4)));
typedef float f32x4 __attribute__((ext_vector_type(4)));

__device__ __forceinline__ float sigm(float x) { return 1.f / (1.f + __expf(-x)); }
__device__ __forceinline__ float tanh_(float x) {
  float e = __expf(2.f * x);
  return 1.f - 2.f / (e + 1.f);
}

__device__ __forceinline__ f32x4 mm3(f16x8 ah, f16x8 al, f16x8 bh, f16x8 bl, f32x4 acc) {
  acc = __builtin_amdgcn_mfma_f32_16x16x32_f16(ah, bh, acc, 0, 0, 0);
  acc = __builtin_amdgcn_mfma_f32_16x16x32_f16(ah, bl, acc, 0, 0, 0);
  acc = __builtin_amdgcn_mfma_f32_16x16x32_f16(al, bh, acc, 0, 0, 0);
  return acc;
}

// split 8 consecutive fp32 into hi/lo fp16 registers
__device__ __forceinline__ void split8(const float* p, f16x8& hi, f16x8& lo) {
  float4 u0 = *(const float4*)p, u1 = *(const float4*)(p + 4);
  float vv[8] = {u0.x, u0.y, u0.z, u0.w, u1.x, u1.y, u1.z, u1.w};
#pragma unroll
  for (int j = 0; j < 8; ++j) {
    _Float16 hj = (_Float16)vv[j];
    hi[j] = hj;
    lo[j] = (_Float16)(vv[j] - (float)hj);
  }
}

// split from transposed LDS activation buffer [col][seq], row stride 68
__device__ __forceinline__ void split8T(const float* base, int kbase, int seq,
                                        f16x8& hi, f16x8& lo) {
  float vv[8];
#pragma unroll
  for (int j = 0; j < 8; ++j) vv[j] = base[(kbase + j) * 68 + seq];
#pragma unroll
  for (int j = 0; j < 8; ++j) {
    _Float16 hj = (_Float16)vv[j];
    hi[j] = hj;
    lo[j] = (_Float16)(vv[j] - (float)hj);
  }
}

// pack fp32 -> (f16 hi | f16 lo << 16)
__device__ __forceinline__ unsigned int packf(float v) {
  _Float16 h = (_Float16)v;
  _Float16 l = (_Float16)(v - (float)h);
  unsigned short uh = __builtin_bit_cast(unsigned short, h);
  unsigned short ul = __builtin_bit_cast(unsigned short, l);
  return (unsigned int)uh | ((unsigned int)ul << 16);
}
// unpack one packed word -> fp32 (hi+lo)
__device__ __forceinline__ float up2(unsigned int w) {
  _Float16 h = __builtin_bit_cast(_Float16, (unsigned short)(w & 0xFFFFu));
  _Float16 l = __builtin_bit_cast(_Float16, (unsigned short)(w >> 16));
  return (float)h + (float)l;
}
// unpack 8 packed words -> hi/lo f16x8 fragments
__device__ __forceinline__ void unpack8(const unsigned int* w, f16x8& hi, f16x8& lo) {
#pragma unroll
  for (int j = 0; j < 8; ++j) {
    hi[j] = __builtin_bit_cast(_Float16, (unsigned short)(w[j] & 0xFFFFu));
    lo[j] = __builtin_bit_cast(_Float16, (unsigned short)(w[j] >> 16));
  }
}

// ---------------------------------------------------------------------------
// Stage 1 v3: per-node MLP (8 -> 64 relu -> 64) as fp16x3 MFMA GEMM.
// ---------------------------------------------------------------------------
__global__ __launch_bounds__(256, 2) void conv_kernel(
    const float* __restrict__ nf, const float* __restrict__ w1,
    const float* __restrict__ b1, const float* __restrict__ w2,
    const float* __restrict__ b2, unsigned int* __restrict__ hpk) {
  __shared__ unsigned int act[256 * 68];   // 69632 B
  int tid = threadIdx.x;
  int w = tid >> 6, lane = tid & 63;
  int q = lane >> 4, i = lane & 15;
  int flat0 = blockIdx.x * 256;            // 256 consecutive (b,t,n) nodes
  int bb = flat0 >> 16;
  int t = (flat0 >> 12) & 15;
  int n0 = flat0 & 4095;

  f16x8 w1h[4], w1l[4];
  f16x8 w2h[4][2], w2l[4][2];
  float bias1[4], bias2[4];
#pragma unroll
  for (int nt = 0; nt < 4; ++nt) {
    int n = nt * 16 + i;
    if (q == 0) split8(w1 + n * 8, w1h[nt], w1l[nt]);
    else { w1h[nt] = (f16x8)0; w1l[nt] = (f16x8)0; }
#pragma unroll
    for (int ks = 0; ks < 2; ++ks)
      split8(w2 + n * 64 + ks * 32 + q * 8, w2h[nt][ks], w2l[nt][ks]);
    bias1[nt] = b1[n];
    bias2[nt] = b2[n];
  }

  // ---- layer 1 ----
  f16x8 xh[4], xl[4];
#pragma unroll
  for (int Mt = 0; Mt < 4; ++Mt) {
    if (q == 0)
      split8(nf + (size_t)(flat0 + w * 64 + Mt * 16 + i) * 8, xh[Mt], xl[Mt]);
    else { xh[Mt] = (f16x8)0; xl[Mt] = (f16x8)0; }
  }
#pragma unroll
  for (int Mt = 0; Mt < 4; ++Mt)
#pragma unroll
    for (int nt = 0; nt < 4; ++nt) {
      f32x4 acc = {bias1[nt], bias1[nt], bias1[nt], bias1[nt]};
      acc = mm3(xh[Mt], xl[Mt], w1h[nt], w1l[nt], acc);
#pragma unroll
      for (int r = 0; r < 4; ++r)
        act[(w * 64 + Mt * 16 + q * 4 + r) * 68 + nt * 16 + i] =
            packf(fmaxf(acc[r], 0.f));
    }
  __syncthreads();

  // ---- layer 2 ----
  f32x4 acc2[4][4];
#pragma unroll
  for (int Mt = 0; Mt < 4; ++Mt)
#pragma unroll
    for (int nt = 0; nt < 4; ++nt) {
      acc2[Mt][nt][0] = bias2[nt]; acc2[Mt][nt][1] = bias2[nt];
      acc2[Mt][nt][2] = bias2[nt]; acc2[Mt][nt][3] = bias2[nt];
    }
#pragma unroll
  for (int ks = 0; ks < 2; ++ks)
#pragma unroll
    for (int Mt = 0; Mt < 4; ++Mt) {
      const unsigned int* p = &act[(w * 64 + Mt * 16 + i) * 68 + ks * 32 + q * 8];
      unsigned int wd[8];
#pragma unroll
      for (int j = 0; j < 4; ++j) {
        uint2 u = *(const uint2*)(p + j * 2);
        wd[2 * j] = u.x; wd[2 * j + 1] = u.y;
      }
      f16x8 ah, al;
      unpack8(wd, ah, al);
#pragma unroll
      for (int nt = 0; nt < 4; ++nt)
        acc2[Mt][nt] = mm3(ah, al, w2h[nt][ks], w2l[nt][ks], acc2[Mt][nt]);
    }
  __syncthreads();   // all act reads done
#pragma unroll
  for (int Mt = 0; Mt < 4; ++Mt)
#pragma unroll
    for (int nt = 0; nt < 4; ++nt)
#pragma unroll
      for (int r = 0; r < 4; ++r)
        act[(w * 64 + Mt * 16 + q * 4 + r) * 68 + nt * 16 + i] =
            packf(acc2[Mt][nt][r]);
  __syncthreads();
  size_t tbase = ((size_t)t * kBN + (size_t)bb * kN + n0) * 64;
#pragma unroll
  for (int k = 0; k < 16; ++k) {
    int d0 = (k * 256 + tid) * 4;
    int node = d0 >> 6, ch = d0 & 63;
    uint2 a = *(const uint2*)&act[node * 68 + ch];
    uint2 b = *(const uint2*)&act[node * 68 + ch + 2];
    uint4 vv = {a.x, a.y, b.x, b.y};
    *(uint4*)(hpk + tbase + d0) = vv;
  }
}

// ---------------------------------------------------------------------------
// Stage 2a: per-(t,dst) edge count (int atomics only)
// ---------------------------------------------------------------------------
__global__ __launch_bounds__(256) void count_kernel(
    const int* __restrict__ ei, int* __restrict__ cnt) {
  int i = blockIdx.x * 256 + threadIdx.x;   // over T*E
  int t = i >> 15, e = i & (kE - 1);
  int dst = ei[t * 2 * kE + kE + e];
  atomicAdd(&cnt[t * kN + dst], 1);
}

// ---------------------------------------------------------------------------
// Stage 2b: per-t exclusive scan over 4096 counts -> offsets + cursor copy.
// ---------------------------------------------------------------------------
__global__ __launch_bounds__(1024) void scan_kernel(
    const int* __restrict__ cnt, int* __restrict__ off, int* __restrict__ cur) {
  __shared__ int sdata[1024];
  int t = blockIdx.x;
  int tid = threadIdx.x;
  const int* c = cnt + t * kN;
  int v0 = c[tid * 4], v1 = c[tid * 4 + 1], v2 = c[tid * 4 + 2], v3 = c[tid * 4 + 3];
  int s = v0 + v1 + v2 + v3;
  sdata[tid] = s;
  __syncthreads();
  for (int d = 1; d < 1024; d <<= 1) {
    int add = (tid >= d) ? sdata[tid - d] : 0;
    __syncthreads();
    sdata[tid] += add;
    __syncthreads();
  }
  int base = sdata[tid] - s;
  int o = t * kN + tid * 4;
  off[o] = base;            cur[o] = base;
  off[o + 1] = base + v0;   cur[o + 1] = base + v0;
  off[o + 2] = base + v0 + v1;        cur[o + 2] = base + v0 + v1;
  off[o + 3] = base + v0 + v1 + v2;   cur[o + 3] = base + v0 + v1 + v2;
}

// ---------------------------------------------------------------------------
// Stage 2c: CSR placement — csr[t*E + pos] = src
// ---------------------------------------------------------------------------
__global__ __launch_bounds__(256) void place_kernel(
    const int* __restrict__ ei, int* __restrict__ cur, int* __restrict__ csr) {
  int i = blockIdx.x * 256 + threadIdx.x;
  int t = i >> 15, e = i & (kE - 1);
  int src = ei[t * 2 * kE + e];
  int dst = ei[t * 2 * kE + kE + e];
  int pos = atomicAdd(&cur[t * kN + dst], 1);
  csr[t * kE + pos] = src;
}

// ---------------------------------------------------------------------------
// Stage 2d: gather + combine, XCD-locality swizzled. Block -> (t, d-range)
// mapping keeps each t-slice (4 MB of hpk) on one XCD's L2: blockIdx%8 = XCD
// (round-robin heuristic), first half of grid does t=0..7, second t=8..15.
// Wave per (t,dst); lane = (batch, channel-quad).
// ---------------------------------------------------------------------------
__global__ __launch_bounds__(256) void gather_kernel(
    const unsigned int* __restrict__ hpk, const int* __restrict__ csr,
    const int* __restrict__ off, const int* __restrict__ cnt,
    _Float16* __restrict__ xhi, _Float16* __restrict__ xlo) {
  int blk = blockIdx.x;
  int t = (blk & 7) | ((blk >> 13) << 3);         // xcd-pinned t
  int idx = (blk >> 3) & 1023;
  int d = idx * 4 + (threadIdx.x >> 6);
  int lane = threadIdx.x & 63;
  int b = lane >> 4, cq = lane & 15;              // batch, channel quad
  int o = off[t * kN + d];
  int c = cnt[t * kN + d];
  size_t tb = ((size_t)t * kBN + (size_t)b * kN) * 64 + cq * 4;
  const int* cs = csr + t * kE + o;
  float s[4] = {0.f, 0.f, 0.f, 0.f};
  int j = 0;
  for (; j + 4 <= c; j += 4) {
    int i0 = cs[j], i1 = cs[j + 1], i2 = cs[j + 2], i3 = cs[j + 3];
    uint4 v0 = *(const uint4*)(hpk + tb + (size_t)i0 * 64);
    uint4 v1 = *(const uint4*)(hpk + tb + (size_t)i1 * 64);
    uint4 v2 = *(const uint4*)(hpk + tb + (size_t)i2 * 64);
    uint4 v3 = *(const uint4*)(hpk + tb + (size_t)i3 * 64);
    s[0] += up2(v0.x) + up2(v1.x) + up2(v2.x) + up2(v3.x);
    s[1] += up2(v0.y) + up2(v1.y) + up2(v2.y) + up2(v3.y);
    s[2] += up2(v0.z) + up2(v1.z) + up2(v2.z) + up2(v3.z);
    s[3] += up2(v0.w) + up2(v1.w) + up2(v2.w) + up2(v3.w);
  }
  for (; j < c; ++j) {
    int i0 = cs[j];
    uint4 v0 = *(const uint4*)(hpk + tb + (size_t)i0 * 64);
    s[0] += up2(v0.x); s[1] += up2(v0.y); s[2] += up2(v0.z); s[3] += up2(v0.w);
  }
  uint4 hv = *(const uint4*)(hpk + tb + (size_t)d * 64);
  float hvf[4] = {up2(hv.x), up2(hv.y), up2(hv.z), up2(hv.w)};
  f16x4 ohi, olo;
  float inv = (c > 0) ? 1.f / (float)c : 0.f;
#pragma unroll
  for (int u = 0; u < 4; ++u) {
    float ov = (c > 0) ? (hvf[u] + s[u] * inv) * 0.5f : hvf[u];
    _Float16 hi = (_Float16)ov;
    ohi[u] = hi;
    olo[u] = (_Float16)(ov - (float)hi);
  }
  *(f16x4*)(xhi + tb + (size_t)d * 64) = ohi;
  *(f16x4*)(xlo + tb + (size_t)d * 64) = olo;
}

// ---------------------------------------------------------------------------
// Stage 3 v6: fused 2-layer LSTM, producer-consumer wave specialization.
// Block = 512 thr (8 waves): waves 0-3 = layer 1, waves 4-7 = layer 2,
// pipelined one t apart. h1 passes through LDS only. y(t-1) stored
// COALESCED from the h2f fragments already ds_read for the recurrent MFMA,
// with the 4 (ml,ks) combos partitioned across the 4 layer-2 waves (no
// duplication); y(15) in an epilogue. Weights in registers (AGPR-parked).
// ---------------------------------------------------------------------------
__global__ __launch_bounds__(512, 2) void lstm2_kernel(
    const _Float16* __restrict__ xhi, const _Float16* __restrict__ xlo,
    _Float16* __restrict__ yhi, _Float16* __restrict__ ylo,
    const float* __restrict__ wih0, const float* __restrict__ whh0,
    const float* __restrict__ bih0, const float* __restrict__ bhh0,
    const float* __restrict__ wih1, const float* __restrict__ whh1,
    const float* __restrict__ bih1, const float* __restrict__ bhh1) {
  __shared__ _Float16 h1f[2][2][2][2][512];  // [buf][ml][ks][hl][lane*8+j] 16KB
  __shared__ _Float16 h2f[2][2][2][2][512];  // 16KB
  int tid = threadIdx.x;
  int grp = tid >> 8;                  // 0 = layer 1, 1 = layer 2
  int cb = (tid >> 6) & 3, lane = tid & 63;
  int q = lane >> 4, i = lane & 15;
  int s0 = blockIdx.x * 32;
  // store-duty partition for layer-2 waves: wave cb stores (ml,ks) combo
  int sml = cb & 1, sks = cb >> 1;

  const float* Wih = grp ? wih1 : wih0;
  const float* Whh = grp ? whh1 : whh0;
  const float* Bih = grp ? bih1 : bih0;
  const float* Bhh = grp ? bhh1 : bhh0;

  // weights -> registers, B-frag order (hi/lo split)
  f16x8 wr[2][4][2][2];   // [mat][g][ks][hl]
#pragma unroll
  for (int mat = 0; mat < 2; ++mat) {
    const float* W = mat ? Whh : Wih;
#pragma unroll
    for (int g = 0; g < 4; ++g) {
      int row = (g * 4 + cb) * 16 + i;
#pragma unroll
      for (int ks = 0; ks < 2; ++ks)
        split8(W + row * 64 + ks * 32 + q * 8, wr[mat][g][ks][0], wr[mat][g][ks][1]);
    }
  }
  int ch = cb * 16 + i;
  float bias4[4];
#pragma unroll
  for (int g = 0; g < 4; ++g) bias4[g] = Bih[g * 64 + ch] + Bhh[g * 64 + ch];
  float cst[2][4];
#pragma unroll
  for (int ml = 0; ml < 2; ++ml)
#pragma unroll
    for (int r = 0; r < 4; ++r) cst[ml][r] = 0.f;
  int ks2 = ch >> 5, q2 = (ch >> 3) & 3, j2 = ch & 7;
  int p = 0;

  for (int it = 0; it < kT + 1; ++it) {
    if (grp == 0) {
      // ---------------- layer 1, t = it ----------------
      if (it < kT) {
        int t = it;
        f32x4 acc[2][4];
#pragma unroll
        for (int ml = 0; ml < 2; ++ml)
#pragma unroll
          for (int g = 0; g < 4; ++g) {
            acc[ml][g][0] = bias4[g]; acc[ml][g][1] = bias4[g];
            acc[ml][g][2] = bias4[g]; acc[ml][g][3] = bias4[g];
          }
        // x contribution from global
#pragma unroll
        for (int ks = 0; ks < 2; ++ks) {
          f16x8 xah[2], xal[2];
#pragma unroll
          for (int ml = 0; ml < 2; ++ml) {
            size_t base = ((size_t)t * kBN + s0 + ml * 16 + i) * 64 + ks * 32 + q * 8;
            xah[ml] = *(const f16x8*)(xhi + base);
            xal[ml] = *(const f16x8*)(xlo + base);
          }
#pragma unroll
          for (int g = 0; g < 4; ++g)
#pragma unroll
            for (int ml = 0; ml < 2; ++ml)
              acc[ml][g] = mm3(xah[ml], xal[ml], wr[0][g][ks][0], wr[0][g][ks][1], acc[ml][g]);
        }
        // recurrent contribution
        if (t > 0) {
#pragma unroll
          for (int ks = 0; ks < 2; ++ks) {
            f16x8 hah[2], hal[2];
#pragma unroll
            for (int ml = 0; ml < 2; ++ml) {
              hah[ml] = *(const f16x8*)&h1f[p][ml][ks][0][lane * 8];
              hal[ml] = *(const f16x8*)&h1f[p][ml][ks][1][lane * 8];
            }
#pragma unroll
            for (int g = 0; g < 4; ++g)
#pragma unroll
              for (int ml = 0; ml < 2; ++ml)
                acc[ml][g] = mm3(hah[ml], hal[ml], wr[1][g][ks][0], wr[1][g][ks][1], acc[ml][g]);
          }
        }
        // gates -> h1(t) -> LDS frags only (no global)
#pragma unroll
        for (int ml = 0; ml < 2; ++ml)
#pragma unroll
          for (int r = 0; r < 4; ++r) {
            float zi = acc[ml][0][r], zf = acc[ml][1][r];
            float zg = acc[ml][2][r], zo = acc[ml][3][r];
            float ig = sigm(zi), fg = sigm(zf), gg = tanh_(zg), og = sigm(zo);
            float c = fg * cst[ml][r] + ig * gg;
            cst[ml][r] = c;
            float hv = og * tanh_(c);
            int row = q * 4 + r;
            _Float16 hh = (_Float16)hv;
            _Float16 hl = (_Float16)(hv - (float)hh);
            int lane2 = q2 * 16 + row;
            h1f[p ^ 1][ml][ks2][0][lane2 * 8 + j2] = hh;
            h1f[p ^ 1][ml][ks2][1][lane2 * 8 + j2] = hl;
          }
      }
    } else {
      // ---------------- layer 2, t = it - 1 ----------------
      if (it >= 1) {
        int t = it - 1;
        f32x4 acc[2][4];
#pragma unroll
        for (int ml = 0; ml < 2; ++ml)
#pragma unroll
          for (int g = 0; g < 4; ++g) {
            acc[ml][g][0] = bias4[g]; acc[ml][g][1] = bias4[g];
            acc[ml][g][2] = bias4[g]; acc[ml][g][3] = bias4[g];
          }
        // input contribution: h1(t) from LDS (A-frag layout already)
#pragma unroll
        for (int ks = 0; ks < 2; ++ks) {
          f16x8 xah[2], xal[2];
#pragma unroll
          for (int ml = 0; ml < 2; ++ml) {
            xah[ml] = *(const f16x8*)&h1f[p][ml][ks][0][lane * 8];
            xal[ml] = *(const f16x8*)&h1f[p][ml][ks][1][lane * 8];
          }
#pragma unroll
          for (int g = 0; g < 4; ++g)
#pragma unroll
            for (int ml = 0; ml < 2; ++ml)
              acc[ml][g] = mm3(xah[ml], xal[ml], wr[0][g][ks][0], wr[0][g][ks][1], acc[ml][g]);
        }
        // recurrent contribution + coalesced y(t-1) store (duty-partitioned)
        if (t > 0) {
#pragma unroll
          for (int ks = 0; ks < 2; ++ks) {
            f16x8 hah[2], hal[2];
#pragma unroll
            for (int ml = 0; ml < 2; ++ml) {
              hah[ml] = *(const f16x8*)&h2f[p][ml][ks][0][lane * 8];
              hal[ml] = *(const f16x8*)&h2f[p][ml][ks][1][lane * 8];
            }
            if (ks == sks) {
              size_t ob = ((size_t)(t - 1) * kBN + s0 + sml * 16 + i) * 64 + ks * 32 + q * 8;
              *(f16x8*)(yhi + ob) = hah[sml];
              *(f16x8*)(ylo + ob) = hal[sml];
            }
#pragma unroll
            for (int g = 0; g < 4; ++g)
#pragma unroll
              for (int ml = 0; ml < 2; ++ml)
                acc[ml][g] = mm3(hah[ml], hal[ml], wr[1][g][ks][0], wr[1][g][ks][1], acc[ml][g]);
          }
        }
        // gates -> h2(t) -> LDS frags (global store deferred to next iter)
#pragma unroll
        for (int ml = 0; ml < 2; ++ml)
#pragma unroll
          for (int r = 0; r < 4; ++r) {
            float zi = acc[ml][0][r], zf = acc[ml][1][r];
            float zg = acc[ml][2][r], zo = acc[ml][3][r];
            float ig = sigm(zi), fg = sigm(zf), gg = tanh_(zg), og = sigm(zo);
            float c = fg * cst[ml][r] + ig * gg;
            cst[ml][r] = c;
            float hv = og * tanh_(c);
            int row = q * 4 + r;
            _Float16 hh = (_Float16)hv;
            _Float16 hl = (_Float16)(hv - (float)hh);
            int lane2 = q2 * 16 + row;
            h2f[p ^ 1][ml][ks2][0][lane2 * 8 + j2] = hh;
            h2f[p ^ 1][ml][ks2][1][lane2 * 8 + j2] = hl;
          }
      }
    }
    __syncthreads();
    p ^= 1;
  }
  // ---- epilogue: layer-2 waves store y(14) pending? no — y(14) stored at
  // it=16 (t=15, t-1=14). Remaining: y(15) from final h2f[p]. ----
  if (grp == 1) {
    f16x8 hah = *(const f16x8*)&h2f[p][sml][sks][0][lane * 8];
    f16x8 hal = *(const f16x8*)&h2f[p][sml][sks][1][lane * 8];
    size_t ob = ((size_t)15 * kBN + s0 + sml * 16 + i) * 64 + sks * 32 + q * 8;
    *(f16x8*)(yhi + ob) = hah;
    *(f16x8*)(ylo + ob) = hal;
  }
}

// ---------------------------------------------------------------------------
// Weight-fragment stagers for the head (B-frag order, fp16 hi/lo).
// ---------------------------------------------------------------------------
__device__ __forceinline__ void stage_frags64(const float* W, _Float16* base,
                                              int O, int tid) {
  int total = O * 16;
  for (int idx = tid; idx < total; idx += 256) {
    int r = idx >> 4, k4 = idx & 15;
    float4 v = *(const float4*)&W[r * 64 + k4 * 4];
    int k = k4 * 4;
    int nt = r >> 4, ii = r & 15, ks = k >> 5, qq = (k >> 3) & 3, j0 = k & 7;
    _Float16* dh = base + ((nt * 2 + ks) * 2) * 512 + (qq * 16 + ii) * 8 + j0;
    _Float16* dl = dh + 512;
    float vv[4] = {v.x, v.y, v.z, v.w};
#pragma unroll
    for (int u = 0; u < 4; ++u) {
      _Float16 hh = (_Float16)vv[u];
      dh[u] = hh;
      dl[u] = (_Float16)(vv[u] - (float)hh);
    }
  }
}

__device__ __forceinline__ void stage_frags128(const float* W, _Float16* base,
                                               int O, int tid) {
  int total = O * 32;
  for (int idx = tid; idx < total; idx += 256) {
    int r = idx >> 5, k4 = idx & 31;
    float4 v = *(const float4*)&W[r * 128 + k4 * 4];
    int k = k4 * 4;
    int nt = r >> 4, ii = r & 15, ks = k >> 5, qq = (k >> 3) & 3, j0 = k & 7;
    _Float16* dh = base + ((nt * 4 + ks) * 2) * 512 + (qq * 16 + ii) * 8 + j0;
    _Float16* dl = dh + 512;
    float vv[4] = {v.x, v.y, v.z, v.w};
#pragma unroll
    for (int u = 0; u < 4; ++u) {
      _Float16 hh = (_Float16)vv[u];
      dh[u] = hh;
      dl[u] = (_Float16)(vv[u] - (float)hh);
    }
  }
}

// ---------------------------------------------------------------------------
// Stage 4 v3: fused attention + head MLP, fp16x3 MFMA; x input is f16 hi/lo.
// ---------------------------------------------------------------------------
__global__ __launch_bounds__(256, 1) void head_kernel(
    const _Float16* __restrict__ xhi, const _Float16* __restrict__ xlo,
    const float* __restrict__ win, const float* __restrict__ bin,
    const float* __restrict__ wout, const float* __restrict__ bout,
    const float* __restrict__ pw1, const float* __restrict__ pb1,
    const float* __restrict__ pw2, const float* __restrict__ pb2,
    const float* __restrict__ pw3, const float* __restrict__ pb3,
    float* __restrict__ out) {
  __shared__ __align__(16) float smem[30720];   // 120 KB
  _Float16* wb = (_Float16*)smem;               // 84 KB weight frags
  float* buf = smem + 21504;                    // 36 KB activations

  int tid = threadIdx.x;
  int w = tid >> 6, lane = tid & 63;
  int q = lane >> 4, i = lane & 15;
  int s0 = blockIdx.x * 64;

  stage_frags64(win, wb, 64, tid);                 // Wq
  stage_frags64(win + 64 * 64, wb + 8192, 128, tid);  // Wkv
  __syncthreads();

  // ---- q projection at t=15 ----
  {
    f16x8 ah[2], al[2];
#pragma unroll
    for (int ks = 0; ks < 2; ++ks) {
      size_t base = ((size_t)15 * kBN + s0 + w * 16 + i) * 64 + ks * 32 + q * 8;
      ah[ks] = *(const f16x8*)(xhi + base);
      al[ks] = *(const f16x8*)(xlo + base);
    }
#pragma unroll
    for (int nt = 0; nt < 4; ++nt) {
      float bias = bin[nt * 16 + i];
      f32x4 acc = {bias, bias, bias, bias};
#pragma unroll
      for (int ks = 0; ks < 2; ++ks) {
        const _Float16* bp = wb + ((nt * 2 + ks) * 2) * 512 + lane * 8;
        acc = mm3(ah[ks], al[ks], *(const f16x8*)bp, *(const f16x8*)(bp + 512), acc);
      }
      *(float4*)&buf[(nt * 16 + i) * 68 + w * 16 + q * 4] = *(float4*)&acc;
    }
  }
  __syncthreads();
  float qreg[16];
#pragma unroll
  for (int d = 0; d < 16; ++d) qreg[d] = buf[(w * 16 + d) * 68 + lane];
  __syncthreads();

  // ---- t loop: kv projection via MFMA + online-softmax attention ----
  float m = -1e30f, l = 0.f;
  float o[16];
#pragma unroll
  for (int d = 0; d < 16; ++d) o[d] = 0.f;

  for (int t = 0; t < kT; ++t) {
    f16x8 xah[4][2], xal[4][2];
#pragma unroll
    for (int Mt = 0; Mt < 4; ++Mt)
#pragma unroll
      for (int ks = 0; ks < 2; ++ks) {
        size_t base = ((size_t)t * kBN + s0 + Mt * 16 + i) * 64 + ks * 32 + q * 8;
        xah[Mt][ks] = *(const f16x8*)(xhi + base);
        xal[Mt][ks] = *(const f16x8*)(xlo + base);
      }
#pragma unroll
    for (int u = 0; u < 2; ++u) {
      int nt = 2 * w + u;                    // cols 0..63 = k, 64..127 = v
      float bias = bin[64 + nt * 16 + i];
      f16x8 bh[2], bl[2];
#pragma unroll
      for (int ks = 0; ks < 2; ++ks) {
        const _Float16* bp = wb + 8192 + ((nt * 2 + ks) * 2) * 512 + lane * 8;
        bh[ks] = *(const f16x8*)bp;
        bl[ks] = *(const f16x8*)(bp + 512);
      }
#pragma unroll
      for (int Mt = 0; Mt < 4; ++Mt) {
        f32x4 acc = {bias, bias, bias, bias};
#pragma unroll
        for (int ks = 0; ks < 2; ++ks)
          acc = mm3(xah[Mt][ks], xal[Mt][ks], bh[ks], bl[ks], acc);
        *(float4*)&buf[(nt * 16 + i) * 68 + Mt * 16 + q * 4] = *(float4*)&acc;
      }
    }
    __syncthreads();
    float sc = 0.f;
#pragma unroll
    for (int d = 0; d < 16; ++d) sc += qreg[d] * buf[(w * 16 + d) * 68 + lane];
    sc *= 0.25f;   // 1/sqrt(HD=16)
    float mn = fmaxf(m, sc);
    float alpha = __expf(m - mn);
    float pp = __expf(sc - mn);
    l = l * alpha + pp;
#pragma unroll
    for (int d = 0; d < 16; ++d)
      o[d] = o[d] * alpha + pp * buf[(64 + w * 16 + d) * 68 + lane];
    m = mn;
    __syncthreads();
  }

  // ---- write normalized o (transposed, cols 0..63) ----
  float linv = 1.f / l;
#pragma unroll
  for (int d = 0; d < 16; ++d) buf[(w * 16 + d) * 68 + lane] = o[d] * linv;
  __syncthreads();

  // ---- restage phase-B weights ----
  stage_frags64(wout, wb, 64, tid);
  stage_frags64(pw1, wb + 8192, 128, tid);
  stage_frags128(pw2, wb + 24576, 64, tid);
  for (int idx = tid; idx < 256; idx += 256) {   // pw3 padded to 16 rows
    int r = idx >> 4, k4 = idx & 15;
    float4 v = {0.f, 0.f, 0.f, 0.f};
    if (r < kNC) v = *(const float4*)&pw3[r * 64 + k4 * 4];
    int k = k4 * 4;
    int ks = k >> 5, qq = (k >> 3) & 3, j0 = k & 7;
    _Float16* dh = wb + 40960 + (ks * 2) * 512 + (qq * 16 + r) * 8 + j0;
    _Float16* dl = dh + 512;
    float vv[4] = {v.x, v.y, v.z, v.w};
#pragma unroll
    for (int u = 0; u < 4; ++u) {
      _Float16 hh = (_Float16)vv[u];
      dh[u] = hh;
      dl[u] = (_Float16)(vv[u] - (float)hh);
    }
  }
  __syncthreads();

  int seq = w * 16 + i;

  // ---- out projection ----
  {
    f16x8 ah[2], al[2];
    split8T(buf, q * 8, seq, ah[0], al[0]);
    split8T(buf, 32 + q * 8, seq, ah[1], al[1]);
#pragma unroll
    for (int nt = 0; nt < 4; ++nt) {
      float bias = bout[nt * 16 + i];
      f32x4 acc = {bias, bias, bias, bias};
#pragma unroll
      for (int ks = 0; ks < 2; ++ks) {
        const _Float16* bp = wb + ((nt * 2 + ks) * 2) * 512 + lane * 8;
        acc = mm3(ah[ks], al[ks], *(const f16x8*)bp, *(const f16x8*)(bp + 512), acc);
      }
      *(float4*)&buf[4352 + (nt * 16 + i) * 68 + w * 16 + q * 4] = *(float4*)&acc;
    }
  }
  __syncthreads();

  // ---- z1 = relu(fin @ pw1^T + pb1) ----
  {
    f16x8 ah[2], al[2];
    split8T(buf + 4352, q * 8, seq, ah[0], al[0]);
    split8T(buf + 4352, 32 + q * 8, seq, ah[1], al[1]);
    __syncthreads();
#pragma unroll
    for (int nt = 0; nt < 8; ++nt) {
      float bias = pb1[nt * 16 + i];
      f32x4 acc = {bias, bias, bias, bias};
#pragma unroll
      for (int ks = 0; ks < 2; ++ks) {
        const _Float16* bp = wb + 8192 + ((nt * 2 + ks) * 2) * 512 + lane * 8;
        acc = mm3(ah[ks], al[ks], *(const f16x8*)bp, *(const f16x8*)(bp + 512), acc);
      }
      f32x4 r4;
#pragma unroll
      for (int r = 0; r < 4; ++r) r4[r] = fmaxf(acc[r], 0.f);
      *(float4*)&buf[(nt * 16 + i) * 68 + w * 16 + q * 4] = *(float4*)&r4;
    }
  }
  __syncthreads();

  // ---- z2 = relu(z1 @ pw2^T + pb2) ----
  {
    f16x8 ah[4], al[4];
#pragma unroll
    for (int ks = 0; ks < 4; ++ks)
      split8T(buf, ks * 32 + q * 8, seq, ah[ks], al[ks]);
    __syncthreads();
#pragma unroll
    for (int nt = 0; nt < 4; ++nt) {
      float bias = pb2[nt * 16 + i];
      f32x4 acc = {bias, bias, bias, bias};
#pragma unroll
      for (int ks = 0; ks < 4; ++ks) {
        const _Float16* bp = wb + 24576 + ((nt * 4 + ks) * 2) * 512 + lane * 8;
        acc = mm3(ah[ks], al[ks], *(const f16x8*)bp, *(const f16x8*)(bp + 512), acc);
      }
      f32x4 r4;
#pragma unroll
      for (int r = 0; r < 4; ++r) r4[r] = fmaxf(acc[r], 0.f);
      *(float4*)&buf[(nt * 16 + i) * 68 + w * 16 + q * 4] = *(float4*)&r4;
    }
  }
  __syncthreads();

  // ---- logits ----
  {
    f16x8 ah[2], al[2];
    split8T(buf, q * 8, seq, ah[0], al[0]);
    split8T(buf, 32 + q * 8, seq, ah[1], al[1]);
    f32x4 acc = {0.f, 0.f, 0.f, 0.f};
#pragma unroll
    for (int ks = 0; ks < 2; ++ks) {
      const _Float16* bp = wb + 40960 + (ks * 2) * 512 + lane * 8;
      acc = mm3(ah[ks], al[ks], *(const f16x8*)bp, *(const f16x8*)(bp + 512), acc);
    }
    if (i < kNC) {
      float bb = pb3[i];
#pragma unroll
      for (int r = 0; r < 4; ++r)
        out[(size_t)(s0 + w * 16 + q * 4 + r) * kNC + i] = acc[r] + bb;
    }
  }
}

// ---------------------------------------------------------------------------
extern "C" void kernel_launch(void* const* d_in, const int* in_sizes, int n_in,
                              void* d_out, int out_size, void* d_ws, size_t ws_size,
                              hipStream_t stream) {
  const float* nf    = (const float*)d_in[0];
  const int*   ei    = (const int*)d_in[1];
  const float* sc_w1 = (const float*)d_in[2];
  const float* sc_b1 = (const float*)d_in[3];
  const float* sc_w2 = (const float*)d_in[4];
  const float* sc_b2 = (const float*)d_in[5];
  const float* wih0  = (const float*)d_in[6];
  const float* whh0  = (const float*)d_in[7];
  const float* bih0  = (const float*)d_in[8];
  const float* bhh0  = (const float*)d_in[9];
  const float* wih1  = (const float*)d_in[10];
  const float* whh1  = (const float*)d_in[11];
  const float* bih1  = (const float*)d_in[12];
  const float* bhh1  = (const float*)d_in[13];
  const float* win   = (const float*)d_in[14];
  const float* bin   = (const float*)d_in[15];
  const float* wout  = (const float*)d_in[16];
  const float* bout  = (const float*)d_in[17];
  const float* pw1   = (const float*)d_in[18];
  const float* pb1   = (const float*)d_in[19];
  const float* pw2   = (const float*)d_in[20];
  const float* pb2   = (const float*)d_in[21];
  const float* pw3   = (const float*)d_in[22];
  const float* pb3   = (const float*)d_in[23];
  float* out = (float*)d_out;

  const size_t NB = (size_t)kT * kBN * 64;  // 16,777,216 elements per buffer
  unsigned int* Hpk = (unsigned int*)d_ws;  // packed conv output (NB uints)
  _Float16* Ahi = (_Float16*)(Hpk + NB);
  _Float16* Alo = Ahi + NB;
  _Float16* Bhi = Alo + NB;
  _Float16* Blo = Bhi + NB;
  int* cnt = (int*)(Blo + NB);         // T*N
  int* off = cnt + kT * kN;            // T*N
  int* cur = off + kT * kN;            // T*N
  int* csr = cur + kT * kN;            // T*E

  hipMemsetAsync(cnt, 0, (size_t)kT * kN * sizeof(int), stream);

  conv_kernel<<<1024, 256, 0, stream>>>(nf, sc_w1, sc_b1, sc_w2, sc_b2, Hpk);
  count_kernel<<<2048, 256, 0, stream>>>(ei, cnt);
  scan_kernel<<<16, 1024, 0, stream>>>(cnt, off, cur);
  place_kernel<<<2048, 256, 0, stream>>>(ei, cur, csr);
  gather_kernel<<<16384, 256, 0, stream>>>(Hpk, csr, off, cnt, Bhi, Blo);
  lstm2_kernel<<<512, 512, 0, stream>>>(Bhi, Blo, Ahi, Alo,
                                        wih0, whh0, bih0, bhh0,
                                        wih1, whh1, bih1, bhh1);
  head_kernel<<<256, 256, 0, stream>>>(Ahi, Alo, win, bin, wout, bout,
                                       pw1, pb1, pw2, pb2, pw3, pb3, out);
}

// Round 11
// 430.982 us; speedup vs baseline: 1.0687x; 1.0687x over previous
//
#include <hip/hip_runtime.h>

// Problem constants
constexpr int kB  = 4;
constexpr int kT  = 16;
constexpr int kN  = 4096;
constexpr int kBN = kB * kN;      // 16384
constexpr int kE  = 32768;
constexpr int kNC = 13;

typedef _Float16 f16x8 __attribute__((ext_vector_type(8)));
typedef _Float16 f16x4 __attribute__((ext_vector_type(4)));
typedef float f32x4 __attribute__((ext_vector_type(4)));

__device__ __forceinline__ float sigm(float x) { return 1.f / (1.f + __expf(-x)); }
__device__ __forceinline__ float tanh_(float x) {
  float e = __expf(2.f * x);
  return 1.f - 2.f / (e + 1.f);
}

__device__ __forceinline__ f32x4 mm3(f16x8 ah, f16x8 al, f16x8 bh, f16x8 bl, f32x4 acc) {
  acc = __builtin_amdgcn_mfma_f32_16x16x32_f16(ah, bh, acc, 0, 0, 0);
  acc = __builtin_amdgcn_mfma_f32_16x16x32_f16(ah, bl, acc, 0, 0, 0);
  acc = __builtin_amdgcn_mfma_f32_16x16x32_f16(al, bh, acc, 0, 0, 0);
  return acc;
}

// split 8 consecutive fp32 into hi/lo fp16 registers
__device__ __forceinline__ void split8(const float* p, f16x8& hi, f16x8& lo) {
  float4 u0 = *(const float4*)p, u1 = *(const float4*)(p + 4);
  float vv[8] = {u0.x, u0.y, u0.z, u0.w, u1.x, u1.y, u1.z, u1.w};
#pragma unroll
  for (int j = 0; j < 8; ++j) {
    _Float16 hj = (_Float16)vv[j];
    hi[j] = hj;
    lo[j] = (_Float16)(vv[j] - (float)hj);
  }
}

// split from transposed LDS activation buffer [col][seq], row stride 68
__device__ __forceinline__ void split8T(const float* base, int kbase, int seq,
                                        f16x8& hi, f16x8& lo) {
  float vv[8];
#pragma unroll
  for (int j = 0; j < 8; ++j) vv[j] = base[(kbase + j) * 68 + seq];
#pragma unroll
  for (int j = 0; j < 8; ++j) {
    _Float16 hj = (_Float16)vv[j];
    hi[j] = hj;
    lo[j] = (_Float16)(vv[j] - (float)hj);
  }
}

// pack fp32 -> (f16 hi | f16 lo << 16)
__device__ __forceinline__ unsigned int packf(float v) {
  _Float16 h = (_Float16)v;
  _Float16 l = (_Float16)(v - (float)h);
  unsigned short uh = __builtin_bit_cast(unsigned short, h);
  unsigned short ul = __builtin_bit_cast(unsigned short, l);
  return (unsigned int)uh | ((unsigned int)ul << 16);
}
// unpack one packed word -> fp32 (hi+lo)
__device__ __forceinline__ float up2(unsigned int w) {
  _Float16 h = __builtin_bit_cast(_Float16, (unsigned short)(w & 0xFFFFu));
  _Float16 l = __builtin_bit_cast(_Float16, (unsigned short)(w >> 16));
  return (float)h + (float)l;
}
// unpack 8 packed words -> hi/lo f16x8 fragments
__device__ __forceinline__ void unpack8(const unsigned int* w, f16x8& hi, f16x8& lo) {
#pragma unroll
  for (int j = 0; j < 8; ++j) {
    hi[j] = __builtin_bit_cast(_Float16, (unsigned short)(w[j] & 0xFFFFu));
    lo[j] = __builtin_bit_cast(_Float16, (unsigned short)(w[j] >> 16));
  }
}

// ---------------------------------------------------------------------------
// Stage 1 v3: per-node MLP (8 -> 64 relu -> 64) as fp16x3 MFMA GEMM.
// ---------------------------------------------------------------------------
__global__ __launch_bounds__(256, 2) void conv_kernel(
    const float* __restrict__ nf, const float* __restrict__ w1,
    const float* __restrict__ b1, const float* __restrict__ w2,
    const float* __restrict__ b2, unsigned int* __restrict__ hpk) {
  __shared__ unsigned int act[256 * 68];   // 69632 B
  int tid = threadIdx.x;
  int w = tid >> 6, lane = tid & 63;
  int q = lane >> 4, i = lane & 15;
  int flat0 = blockIdx.x * 256;            // 256 consecutive (b,t,n) nodes
  int bb = flat0 >> 16;
  int t = (flat0 >> 12) & 15;
  int n0 = flat0 & 4095;

  f16x8 w1h[4], w1l[4];
  f16x8 w2h[4][2], w2l[4][2];
  float bias1[4], bias2[4];
#pragma unroll
  for (int nt = 0; nt < 4; ++nt) {
    int n = nt * 16 + i;
    if (q == 0) split8(w1 + n * 8, w1h[nt], w1l[nt]);
    else { w1h[nt] = (f16x8)0; w1l[nt] = (f16x8)0; }
#pragma unroll
    for (int ks = 0; ks < 2; ++ks)
      split8(w2 + n * 64 + ks * 32 + q * 8, w2h[nt][ks], w2l[nt][ks]);
    bias1[nt] = b1[n];
    bias2[nt] = b2[n];
  }

  // ---- layer 1 ----
  f16x8 xh[4], xl[4];
#pragma unroll
  for (int Mt = 0; Mt < 4; ++Mt) {
    if (q == 0)
      split8(nf + (size_t)(flat0 + w * 64 + Mt * 16 + i) * 8, xh[Mt], xl[Mt]);
    else { xh[Mt] = (f16x8)0; xl[Mt] = (f16x8)0; }
  }
#pragma unroll
  for (int Mt = 0; Mt < 4; ++Mt)
#pragma unroll
    for (int nt = 0; nt < 4; ++nt) {
      f32x4 acc = {bias1[nt], bias1[nt], bias1[nt], bias1[nt]};
      acc = mm3(xh[Mt], xl[Mt], w1h[nt], w1l[nt], acc);
#pragma unroll
      for (int r = 0; r < 4; ++r)
        act[(w * 64 + Mt * 16 + q * 4 + r) * 68 + nt * 16 + i] =
            packf(fmaxf(acc[r], 0.f));
    }
  __syncthreads();

  // ---- layer 2 ----
  f32x4 acc2[4][4];
#pragma unroll
  for (int Mt = 0; Mt < 4; ++Mt)
#pragma unroll
    for (int nt = 0; nt < 4; ++nt) {
      acc2[Mt][nt][0] = bias2[nt]; acc2[Mt][nt][1] = bias2[nt];
      acc2[Mt][nt][2] = bias2[nt]; acc2[Mt][nt][3] = bias2[nt];
    }
#pragma unroll
  for (int ks = 0; ks < 2; ++ks)
#pragma unroll
    for (int Mt = 0; Mt < 4; ++Mt) {
      const unsigned int* p = &act[(w * 64 + Mt * 16 + i) * 68 + ks * 32 + q * 8];
      unsigned int wd[8];
#pragma unroll
      for (int j = 0; j < 4; ++j) {
        uint2 u = *(const uint2*)(p + j * 2);
        wd[2 * j] = u.x; wd[2 * j + 1] = u.y;
      }
      f16x8 ah, al;
      unpack8(wd, ah, al);
#pragma unroll
      for (int nt = 0; nt < 4; ++nt)
        acc2[Mt][nt] = mm3(ah, al, w2h[nt][ks], w2l[nt][ks], acc2[Mt][nt]);
    }
  __syncthreads();   // all act reads done
#pragma unroll
  for (int Mt = 0; Mt < 4; ++Mt)
#pragma unroll
    for (int nt = 0; nt < 4; ++nt)
#pragma unroll
      for (int r = 0; r < 4; ++r)
        act[(w * 64 + Mt * 16 + q * 4 + r) * 68 + nt * 16 + i] =
            packf(acc2[Mt][nt][r]);
  __syncthreads();
  size_t tbase = ((size_t)t * kBN + (size_t)bb * kN + n0) * 64;
#pragma unroll
  for (int k = 0; k < 16; ++k) {
    int d0 = (k * 256 + tid) * 4;
    int node = d0 >> 6, ch = d0 & 63;
    uint2 a = *(const uint2*)&act[node * 68 + ch];
    uint2 b = *(const uint2*)&act[node * 68 + ch + 2];
    uint4 vv = {a.x, a.y, b.x, b.y};
    *(uint4*)(hpk + tbase + d0) = vv;
  }
}

// ---------------------------------------------------------------------------
// Stage 2a: per-(t,dst) edge count (int atomics only)
// ---------------------------------------------------------------------------
__global__ __launch_bounds__(256) void count_kernel(
    const int* __restrict__ ei, int* __restrict__ cnt) {
  int i = blockIdx.x * 256 + threadIdx.x;   // over T*E
  int t = i >> 15, e = i & (kE - 1);
  int dst = ei[t * 2 * kE + kE + e];
  atomicAdd(&cnt[t * kN + dst], 1);
}

// ---------------------------------------------------------------------------
// Stage 2b: per-t exclusive scan over 4096 counts -> offsets + cursor copy.
// ---------------------------------------------------------------------------
__global__ __launch_bounds__(1024) void scan_kernel(
    const int* __restrict__ cnt, int* __restrict__ off, int* __restrict__ cur) {
  __shared__ int sdata[1024];
  int t = blockIdx.x;
  int tid = threadIdx.x;
  const int* c = cnt + t * kN;
  int v0 = c[tid * 4], v1 = c[tid * 4 + 1], v2 = c[tid * 4 + 2], v3 = c[tid * 4 + 3];
  int s = v0 + v1 + v2 + v3;
  sdata[tid] = s;
  __syncthreads();
  for (int d = 1; d < 1024; d <<= 1) {
    int add = (tid >= d) ? sdata[tid - d] : 0;
    __syncthreads();
    sdata[tid] += add;
    __syncthreads();
  }
  int base = sdata[tid] - s;
  int o = t * kN + tid * 4;
  off[o] = base;            cur[o] = base;
  off[o + 1] = base + v0;   cur[o + 1] = base + v0;
  off[o + 2] = base + v0 + v1;        cur[o + 2] = base + v0 + v1;
  off[o + 3] = base + v0 + v1 + v2;   cur[o + 3] = base + v0 + v1 + v2;
}

// ---------------------------------------------------------------------------
// Stage 2c: CSR placement — csr[t*E + pos] = src
// ---------------------------------------------------------------------------
__global__ __launch_bounds__(256) void place_kernel(
    const int* __restrict__ ei, int* __restrict__ cur, int* __restrict__ csr) {
  int i = blockIdx.x * 256 + threadIdx.x;
  int t = i >> 15, e = i & (kE - 1);
  int src = ei[t * 2 * kE + e];
  int dst = ei[t * 2 * kE + kE + e];
  int pos = atomicAdd(&cur[t * kN + dst], 1);
  csr[t * kE + pos] = src;
}

// ---------------------------------------------------------------------------
// Stage 2d: gather + combine, XCD-locality swizzled (R9 WIN: -44 us).
// blockIdx%8 = XCD round-robin pins each t-slice (4 MB of hpk) to one XCD L2.
// Wave per (t,dst); lane = (batch, channel-quad).
// ---------------------------------------------------------------------------
__global__ __launch_bounds__(256) void gather_kernel(
    const unsigned int* __restrict__ hpk, const int* __restrict__ csr,
    const int* __restrict__ off, const int* __restrict__ cnt,
    _Float16* __restrict__ xhi, _Float16* __restrict__ xlo) {
  int blk = blockIdx.x;
  int t = (blk & 7) | ((blk >> 13) << 3);         // xcd-pinned t
  int idx = (blk >> 3) & 1023;
  int d = idx * 4 + (threadIdx.x >> 6);
  int lane = threadIdx.x & 63;
  int b = lane >> 4, cq = lane & 15;              // batch, channel quad
  int o = off[t * kN + d];
  int c = cnt[t * kN + d];
  size_t tb = ((size_t)t * kBN + (size_t)b * kN) * 64 + cq * 4;
  const int* cs = csr + t * kE + o;
  float s[4] = {0.f, 0.f, 0.f, 0.f};
  int j = 0;
  for (; j + 4 <= c; j += 4) {
    int i0 = cs[j], i1 = cs[j + 1], i2 = cs[j + 2], i3 = cs[j + 3];
    uint4 v0 = *(const uint4*)(hpk + tb + (size_t)i0 * 64);
    uint4 v1 = *(const uint4*)(hpk + tb + (size_t)i1 * 64);
    uint4 v2 = *(const uint4*)(hpk + tb + (size_t)i2 * 64);
    uint4 v3 = *(const uint4*)(hpk + tb + (size_t)i3 * 64);
    s[0] += up2(v0.x) + up2(v1.x) + up2(v2.x) + up2(v3.x);
    s[1] += up2(v0.y) + up2(v1.y) + up2(v2.y) + up2(v3.y);
    s[2] += up2(v0.z) + up2(v1.z) + up2(v2.z) + up2(v3.z);
    s[3] += up2(v0.w) + up2(v1.w) + up2(v2.w) + up2(v3.w);
  }
  for (; j < c; ++j) {
    int i0 = cs[j];
    uint4 v0 = *(const uint4*)(hpk + tb + (size_t)i0 * 64);
    s[0] += up2(v0.x); s[1] += up2(v0.y); s[2] += up2(v0.z); s[3] += up2(v0.w);
  }
  uint4 hv = *(const uint4*)(hpk + tb + (size_t)d * 64);
  float hvf[4] = {up2(hv.x), up2(hv.y), up2(hv.z), up2(hv.w)};
  f16x4 ohi, olo;
  float inv = (c > 0) ? 1.f / (float)c : 0.f;
#pragma unroll
  for (int u = 0; u < 4; ++u) {
    float ov = (c > 0) ? (hvf[u] + s[u] * inv) * 0.5f : hvf[u];
    _Float16 hi = (_Float16)ov;
    ohi[u] = hi;
    olo[u] = (_Float16)(ov - (float)hi);
  }
  *(f16x4*)(xhi + tb + (size_t)d * 64) = ohi;
  *(f16x4*)(xlo + tb + (size_t)d * 64) = olo;
}

// ---------------------------------------------------------------------------
// Stage 3 (R8-exact, measured 168 us): fused 2-layer LSTM, producer-consumer
// wave specialization. Block = 512 thr (8 waves): waves 0-3 = layer 1,
// waves 4-7 = layer 2, pipelined one t apart. h1 passes via LDS only.
// Layer-2 stores y directly in the gate section (scalar stores — R7/R9
// "coalesced store" variants both regressed; do not touch this path).
// ---------------------------------------------------------------------------
__global__ __launch_bounds__(512, 2) void lstm2_kernel(
    const _Float16* __restrict__ xhi, const _Float16* __restrict__ xlo,
    _Float16* __restrict__ yhi, _Float16* __restrict__ ylo,
    const float* __restrict__ wih0, const float* __restrict__ whh0,
    const float* __restrict__ bih0, const float* __restrict__ bhh0,
    const float* __restrict__ wih1, const float* __restrict__ whh1,
    const float* __restrict__ bih1, const float* __restrict__ bhh1) {
  __shared__ _Float16 h1f[2][2][2][2][512];  // [buf][ml][ks][hl][lane*8+j] 16KB
  __shared__ _Float16 h2f[2][2][2][2][512];  // 16KB
  int tid = threadIdx.x;
  int grp = tid >> 8;                  // 0 = layer 1, 1 = layer 2
  int cb = (tid >> 6) & 3, lane = tid & 63;
  int q = lane >> 4, i = lane & 15;
  int s0 = blockIdx.x * 32;

  const float* Wih = grp ? wih1 : wih0;
  const float* Whh = grp ? whh1 : whh0;
  const float* Bih = grp ? bih1 : bih0;
  const float* Bhh = grp ? bhh1 : bhh0;

  // weights -> registers, B-frag order (hi/lo split)
  f16x8 wr[2][4][2][2];   // [mat][g][ks][hl]
#pragma unroll
  for (int mat = 0; mat < 2; ++mat) {
    const float* W = mat ? Whh : Wih;
#pragma unroll
    for (int g = 0; g < 4; ++g) {
      int row = (g * 4 + cb) * 16 + i;
#pragma unroll
      for (int ks = 0; ks < 2; ++ks)
        split8(W + row * 64 + ks * 32 + q * 8, wr[mat][g][ks][0], wr[mat][g][ks][1]);
    }
  }
  int ch = cb * 16 + i;
  float bias4[4];
#pragma unroll
  for (int g = 0; g < 4; ++g) bias4[g] = Bih[g * 64 + ch] + Bhh[g * 64 + ch];
  float cst[2][4];
#pragma unroll
  for (int ml = 0; ml < 2; ++ml)
#pragma unroll
    for (int r = 0; r < 4; ++r) cst[ml][r] = 0.f;
  int ks2 = ch >> 5, q2 = (ch >> 3) & 3, j2 = ch & 7;
  int p = 0;

  for (int it = 0; it < kT + 1; ++it) {
    if (grp == 0) {
      // ---------------- layer 1, t = it ----------------
      if (it < kT) {
        int t = it;
        f32x4 acc[2][4];
#pragma unroll
        for (int ml = 0; ml < 2; ++ml)
#pragma unroll
          for (int g = 0; g < 4; ++g) {
            acc[ml][g][0] = bias4[g]; acc[ml][g][1] = bias4[g];
            acc[ml][g][2] = bias4[g]; acc[ml][g][3] = bias4[g];
          }
        // x contribution from global
#pragma unroll
        for (int ks = 0; ks < 2; ++ks) {
          f16x8 xah[2], xal[2];
#pragma unroll
          for (int ml = 0; ml < 2; ++ml) {
            size_t base = ((size_t)t * kBN + s0 + ml * 16 + i) * 64 + ks * 32 + q * 8;
            xah[ml] = *(const f16x8*)(xhi + base);
            xal[ml] = *(const f16x8*)(xlo + base);
          }
#pragma unroll
          for (int g = 0; g < 4; ++g)
#pragma unroll
            for (int ml = 0; ml < 2; ++ml)
              acc[ml][g] = mm3(xah[ml], xal[ml], wr[0][g][ks][0], wr[0][g][ks][1], acc[ml][g]);
        }
        // recurrent contribution
        if (t > 0) {
#pragma unroll
          for (int ks = 0; ks < 2; ++ks) {
            f16x8 hah[2], hal[2];
#pragma unroll
            for (int ml = 0; ml < 2; ++ml) {
              hah[ml] = *(const f16x8*)&h1f[p][ml][ks][0][lane * 8];
              hal[ml] = *(const f16x8*)&h1f[p][ml][ks][1][lane * 8];
            }
#pragma unroll
            for (int g = 0; g < 4; ++g)
#pragma unroll
              for (int ml = 0; ml < 2; ++ml)
                acc[ml][g] = mm3(hah[ml], hal[ml], wr[1][g][ks][0], wr[1][g][ks][1], acc[ml][g]);
          }
        }
        // gates -> h1(t) -> LDS frags only (no global)
#pragma unroll
        for (int ml = 0; ml < 2; ++ml)
#pragma unroll
          for (int r = 0; r < 4; ++r) {
            float zi = acc[ml][0][r], zf = acc[ml][1][r];
            float zg = acc[ml][2][r], zo = acc[ml][3][r];
            float ig = sigm(zi), fg = sigm(zf), gg = tanh_(zg), og = sigm(zo);
            float c = fg * cst[ml][r] + ig * gg;
            cst[ml][r] = c;
            float hv = og * tanh_(c);
            int row = q * 4 + r;
            _Float16 hh = (_Float16)hv;
            _Float16 hl = (_Float16)(hv - (float)hh);
            int lane2 = q2 * 16 + row;
            h1f[p ^ 1][ml][ks2][0][lane2 * 8 + j2] = hh;
            h1f[p ^ 1][ml][ks2][1][lane2 * 8 + j2] = hl;
          }
      }
    } else {
      // ---------------- layer 2, t = it - 1 ----------------
      if (it >= 1) {
        int t = it - 1;
        f32x4 acc[2][4];
#pragma unroll
        for (int ml = 0; ml < 2; ++ml)
#pragma unroll
          for (int g = 0; g < 4; ++g) {
            acc[ml][g][0] = bias4[g]; acc[ml][g][1] = bias4[g];
            acc[ml][g][2] = bias4[g]; acc[ml][g][3] = bias4[g];
          }
        // input contribution: h1(t) from LDS (A-frag layout already)
#pragma unroll
        for (int ks = 0; ks < 2; ++ks) {
          f16x8 xah[2], xal[2];
#pragma unroll
          for (int ml = 0; ml < 2; ++ml) {
            xah[ml] = *(const f16x8*)&h1f[p][ml][ks][0][lane * 8];
            xal[ml] = *(const f16x8*)&h1f[p][ml][ks][1][lane * 8];
          }
#pragma unroll
          for (int g = 0; g < 4; ++g)
#pragma unroll
            for (int ml = 0; ml < 2; ++ml)
              acc[ml][g] = mm3(xah[ml], xal[ml], wr[0][g][ks][0], wr[0][g][ks][1], acc[ml][g]);
        }
        // recurrent contribution
        if (t > 0) {
#pragma unroll
          for (int ks = 0; ks < 2; ++ks) {
            f16x8 hah[2], hal[2];
#pragma unroll
            for (int ml = 0; ml < 2; ++ml) {
              hah[ml] = *(const f16x8*)&h2f[p][ml][ks][0][lane * 8];
              hal[ml] = *(const f16x8*)&h2f[p][ml][ks][1][lane * 8];
            }
#pragma unroll
            for (int g = 0; g < 4; ++g)
#pragma unroll
              for (int ml = 0; ml < 2; ++ml)
                acc[ml][g] = mm3(hah[ml], hal[ml], wr[1][g][ks][0], wr[1][g][ks][1], acc[ml][g]);
          }
        }
        // gates -> h2(t) -> global y + LDS frags
#pragma unroll
        for (int ml = 0; ml < 2; ++ml)
#pragma unroll
          for (int r = 0; r < 4; ++r) {
            float zi = acc[ml][0][r], zf = acc[ml][1][r];
            float zg = acc[ml][2][r], zo = acc[ml][3][r];
            float ig = sigm(zi), fg = sigm(zf), gg = tanh_(zg), og = sigm(zo);
            float c = fg * cst[ml][r] + ig * gg;
            cst[ml][r] = c;
            float hv = og * tanh_(c);
            int row = q * 4 + r;
            size_t ob = ((size_t)t * kBN + s0 + ml * 16 + row) * 64 + ch;
            _Float16 hh = (_Float16)hv;
            _Float16 hl = (_Float16)(hv - (float)hh);
            yhi[ob] = hh;
            ylo[ob] = hl;
            int lane2 = q2 * 16 + row;
            h2f[p ^ 1][ml][ks2][0][lane2 * 8 + j2] = hh;
            h2f[p ^ 1][ml][ks2][1][lane2 * 8 + j2] = hl;
          }
      }
    }
    __syncthreads();
    p ^= 1;
  }
}

// ---------------------------------------------------------------------------
// Weight-fragment stagers for the head (B-frag order, fp16 hi/lo).
// ---------------------------------------------------------------------------
__device__ __forceinline__ void stage_frags64(const float* W, _Float16* base,
                                              int O, int tid) {
  int total = O * 16;
  for (int idx = tid; idx < total; idx += 256) {
    int r = idx >> 4, k4 = idx & 15;
    float4 v = *(const float4*)&W[r * 64 + k4 * 4];
    int k = k4 * 4;
    int nt = r >> 4, ii = r & 15, ks = k >> 5, qq = (k >> 3) & 3, j0 = k & 7;
    _Float16* dh = base + ((nt * 2 + ks) * 2) * 512 + (qq * 16 + ii) * 8 + j0;
    _Float16* dl = dh + 512;
    float vv[4] = {v.x, v.y, v.z, v.w};
#pragma unroll
    for (int u = 0; u < 4; ++u) {
      _Float16 hh = (_Float16)vv[u];
      dh[u] = hh;
      dl[u] = (_Float16)(vv[u] - (float)hh);
    }
  }
}

__device__ __forceinline__ void stage_frags128(const float* W, _Float16* base,
                                               int O, int tid) {
  int total = O * 32;
  for (int idx = tid; idx < total; idx += 256) {
    int r = idx >> 5, k4 = idx & 31;
    float4 v = *(const float4*)&W[r * 128 + k4 * 4];
    int k = k4 * 4;
    int nt = r >> 4, ii = r & 15, ks = k >> 5, qq = (k >> 3) & 3, j0 = k & 7;
    _Float16* dh = base + ((nt * 4 + ks) * 2) * 512 + (qq * 16 + ii) * 8 + j0;
    _Float16* dl = dh + 512;
    float vv[4] = {v.x, v.y, v.z, v.w};
#pragma unroll
    for (int u = 0; u < 4; ++u) {
      _Float16 hh = (_Float16)vv[u];
      dh[u] = hh;
      dl[u] = (_Float16)(vv[u] - (float)hh);
    }
  }
}

// ---------------------------------------------------------------------------
// Stage 4 v3: fused attention + head MLP, fp16x3 MFMA; x input is f16 hi/lo.
// ---------------------------------------------------------------------------
__global__ __launch_bounds__(256, 1) void head_kernel(
    const _Float16* __restrict__ xhi, const _Float16* __restrict__ xlo,
    const float* __restrict__ win, const float* __restrict__ bin,
    const float* __restrict__ wout, const float* __restrict__ bout,
    const float* __restrict__ pw1, const float* __restrict__ pb1,
    const float* __restrict__ pw2, const float* __restrict__ pb2,
    const float* __restrict__ pw3, const float* __restrict__ pb3,
    float* __restrict__ out) {
  __shared__ __align__(16) float smem[30720];   // 120 KB
  _Float16* wb = (_Float16*)smem;               // 84 KB weight frags
  float* buf = smem + 21504;                    // 36 KB activations

  int tid = threadIdx.x;
  int w = tid >> 6, lane = tid & 63;
  int q = lane >> 4, i = lane & 15;
  int s0 = blockIdx.x * 64;

  stage_frags64(win, wb, 64, tid);                 // Wq
  stage_frags64(win + 64 * 64, wb + 8192, 128, tid);  // Wkv
  __syncthreads();

  // ---- q projection at t=15 ----
  {
    f16x8 ah[2], al[2];
#pragma unroll
    for (int ks = 0; ks < 2; ++ks) {
      size_t base = ((size_t)15 * kBN + s0 + w * 16 + i) * 64 + ks * 32 + q * 8;
      ah[ks] = *(const f16x8*)(xhi + base);
      al[ks] = *(const f16x8*)(xlo + base);
    }
#pragma unroll
    for (int nt = 0; nt < 4; ++nt) {
      float bias = bin[nt * 16 + i];
      f32x4 acc = {bias, bias, bias, bias};
#pragma unroll
      for (int ks = 0; ks < 2; ++ks) {
        const _Float16* bp = wb + ((nt * 2 + ks) * 2) * 512 + lane * 8;
        acc = mm3(ah[ks], al[ks], *(const f16x8*)bp, *(const f16x8*)(bp + 512), acc);
      }
      *(float4*)&buf[(nt * 16 + i) * 68 + w * 16 + q * 4] = *(float4*)&acc;
    }
  }
  __syncthreads();
  float qreg[16];
#pragma unroll
  for (int d = 0; d < 16; ++d) qreg[d] = buf[(w * 16 + d) * 68 + lane];
  __syncthreads();

  // ---- t loop: kv projection via MFMA + online-softmax attention ----
  float m = -1e30f, l = 0.f;
  float o[16];
#pragma unroll
  for (int d = 0; d < 16; ++d) o[d] = 0.f;

  for (int t = 0; t < kT; ++t) {
    f16x8 xah[4][2], xal[4][2];
#pragma unroll
    for (int Mt = 0; Mt < 4; ++Mt)
#pragma unroll
      for (int ks = 0; ks < 2; ++ks) {
        size_t base = ((size_t)t * kBN + s0 + Mt * 16 + i) * 64 + ks * 32 + q * 8;
        xah[Mt][ks] = *(const f16x8*)(xhi + base);
        xal[Mt][ks] = *(const f16x8*)(xlo + base);
      }
#pragma unroll
    for (int u = 0; u < 2; ++u) {
      int nt = 2 * w + u;                    // cols 0..63 = k, 64..127 = v
      float bias = bin[64 + nt * 16 + i];
      f16x8 bh[2], bl[2];
#pragma unroll
      for (int ks = 0; ks < 2; ++ks) {
        const _Float16* bp = wb + 8192 + ((nt * 2 + ks) * 2) * 512 + lane * 8;
        bh[ks] = *(const f16x8*)bp;
        bl[ks] = *(const f16x8*)(bp + 512);
      }
#pragma unroll
      for (int Mt = 0; Mt < 4; ++Mt) {
        f32x4 acc = {bias, bias, bias, bias};
#pragma unroll
        for (int ks = 0; ks < 2; ++ks)
          acc = mm3(xah[Mt][ks], xal[Mt][ks], bh[ks], bl[ks], acc);
        *(float4*)&buf[(nt * 16 + i) * 68 + Mt * 16 + q * 4] = *(float4*)&acc;
      }
    }
    __syncthreads();
    float sc = 0.f;
#pragma unroll
    for (int d = 0; d < 16; ++d) sc += qreg[d] * buf[(w * 16 + d) * 68 + lane];
    sc *= 0.25f;   // 1/sqrt(HD=16)
    float mn = fmaxf(m, sc);
    float alpha = __expf(m - mn);
    float pp = __expf(sc - mn);
    l = l * alpha + pp;
#pragma unroll
    for (int d = 0; d < 16; ++d)
      o[d] = o[d] * alpha + pp * buf[(64 + w * 16 + d) * 68 + lane];
    m = mn;
    __syncthreads();
  }

  // ---- write normalized o (transposed, cols 0..63) ----
  float linv = 1.f / l;
#pragma unroll
  for (int d = 0; d < 16; ++d) buf[(w * 16 + d) * 68 + lane] = o[d] * linv;
  __syncthreads();

  // ---- restage phase-B weights ----
  stage_frags64(wout, wb, 64, tid);
  stage_frags64(pw1, wb + 8192, 128, tid);
  stage_frags128(pw2, wb + 24576, 64, tid);
  for (int idx = tid; idx < 256; idx += 256) {   // pw3 padded to 16 rows
    int r = idx >> 4, k4 = idx & 15;
    float4 v = {0.f, 0.f, 0.f, 0.f};
    if (r < kNC) v = *(const float4*)&pw3[r * 64 + k4 * 4];
    int k = k4 * 4;
    int ks = k >> 5, qq = (k >> 3) & 3, j0 = k & 7;
    _Float16* dh = wb + 40960 + (ks * 2) * 512 + (qq * 16 + r) * 8 + j0;
    _Float16* dl = dh + 512;
    float vv[4] = {v.x, v.y, v.z, v.w};
#pragma unroll
    for (int u = 0; u < 4; ++u) {
      _Float16 hh = (_Float16)vv[u];
      dh[u] = hh;
      dl[u] = (_Float16)(vv[u] - (float)hh);
    }
  }
  __syncthreads();

  int seq = w * 16 + i;

  // ---- out projection ----
  {
    f16x8 ah[2], al[2];
    split8T(buf, q * 8, seq, ah[0], al[0]);
    split8T(buf, 32 + q * 8, seq, ah[1], al[1]);
#pragma unroll
    for (int nt = 0; nt < 4; ++nt) {
      float bias = bout[nt * 16 + i];
      f32x4 acc = {bias, bias, bias, bias};
#pragma unroll
      for (int ks = 0; ks < 2; ++ks) {
        const _Float16* bp = wb + ((nt * 2 + ks) * 2) * 512 + lane * 8;
        acc = mm3(ah[ks], al[ks], *(const f16x8*)bp, *(const f16x8*)(bp + 512), acc);
      }
      *(float4*)&buf[4352 + (nt * 16 + i) * 68 + w * 16 + q * 4] = *(float4*)&acc;
    }
  }
  __syncthreads();

  // ---- z1 = relu(fin @ pw1^T + pb1) ----
  {
    f16x8 ah[2], al[2];
    split8T(buf + 4352, q * 8, seq, ah[0], al[0]);
    split8T(buf + 4352, 32 + q * 8, seq, ah[1], al[1]);
    __syncthreads();
#pragma unroll
    for (int nt = 0; nt < 8; ++nt) {
      float bias = pb1[nt * 16 + i];
      f32x4 acc = {bias, bias, bias, bias};
#pragma unroll
      for (int ks = 0; ks < 2; ++ks) {
        const _Float16* bp = wb + 8192 + ((nt * 2 + ks) * 2) * 512 + lane * 8;
        acc = mm3(ah[ks], al[ks], *(const f16x8*)bp, *(const f16x8*)(bp + 512), acc);
      }
      f32x4 r4;
#pragma unroll
      for (int r = 0; r < 4; ++r) r4[r] = fmaxf(acc[r], 0.f);
      *(float4*)&buf[(nt * 16 + i) * 68 + w * 16 + q * 4] = *(float4*)&r4;
    }
  }
  __syncthreads();

  // ---- z2 = relu(z1 @ pw2^T + pb2) ----
  {
    f16x8 ah[4], al[4];
#pragma unroll
    for (int ks = 0; ks < 4; ++ks)
      split8T(buf, ks * 32 + q * 8, seq, ah[ks], al[ks]);
    __syncthreads();
#pragma unroll
    for (int nt = 0; nt < 4; ++nt) {
      float bias = pb2[nt * 16 + i];
      f32x4 acc = {bias, bias, bias, bias};
#pragma unroll
      for (int ks = 0; ks < 4; ++ks) {
        const _Float16* bp = wb + 24576 + ((nt * 4 + ks) * 2) * 512 + lane * 8;
        acc = mm3(ah[ks], al[ks], *(const f16x8*)bp, *(const f16x8*)(bp + 512), acc);
      }
      f32x4 r4;
#pragma unroll
      for (int r = 0; r < 4; ++r) r4[r] = fmaxf(acc[r], 0.f);
      *(float4*)&buf[(nt * 16 + i) * 68 + w * 16 + q * 4] = *(float4*)&r4;
    }
  }
  __syncthreads();

  // ---- logits ----
  {
    f16x8 ah[2], al[2];
    split8T(buf, q * 8, seq, ah[0], al[0]);
    split8T(buf, 32 + q * 8, seq, ah[1], al[1]);
    f32x4 acc = {0.f, 0.f, 0.f, 0.f};
#pragma unroll
    for (int ks = 0; ks < 2; ++ks) {
      const _Float16* bp = wb + 40960 + (ks * 2) * 512 + lane * 8;
      acc = mm3(ah[ks], al[ks], *(const f16x8*)bp, *(const f16x8*)(bp + 512), acc);
    }
    if (i < kNC) {
      float bb = pb3[i];
#pragma unroll
      for (int r = 0; r < 4; ++r)
        out[(size_t)(s0 + w * 16 + q * 4 + r) * kNC + i] = acc[r] + bb;
    }
  }
}

// ---------------------------------------------------------------------------
extern "C" void kernel_launch(void* const* d_in, const int* in_sizes, int n_in,
                              void* d_out, int out_size, void* d_ws, size_t ws_size,
                              hipStream_t stream) {
  const float* nf    = (const float*)d_in[0];
  const int*   ei    = (const int*)d_in[1];
  const float* sc_w1 = (const float*)d_in[2];
  const float* sc_b1 = (const float*)d_in[3];
  const float* sc_w2 = (const float*)d_in[4];
  const float* sc_b2 = (const float*)d_in[5];
  const float* wih0  = (const float*)d_in[6];
  const float* whh0  = (const float*)d_in[7];
  const float* bih0  = (const float*)d_in[8];
  const float* bhh0  = (const float*)d_in[9];
  const float* wih1  = (const float*)d_in[10];
  const float* whh1  = (const float*)d_in[11];
  const float* bih1  = (const float*)d_in[12];
  const float* bhh1  = (const float*)d_in[13];
  const float* win   = (const float*)d_in[14];
  const float* bin   = (const float*)d_in[15];
  const float* wout  = (const float*)d_in[16];
  const float* bout  = (const float*)d_in[17];
  const float* pw1   = (const float*)d_in[18];
  const float* pb1   = (const float*)d_in[19];
  const float* pw2   = (const float*)d_in[20];
  const float* pb2   = (const float*)d_in[21];
  const float* pw3   = (const float*)d_in[22];
  const float* pb3   = (const float*)d_in[23];
  float* out = (float*)d_out;

  const size_t NB = (size_t)kT * kBN * 64;  // 16,777,216 elements per buffer
  unsigned int* Hpk = (unsigned int*)d_ws;  // packed conv output (NB uints)
  _Float16* Ahi = (_Float16*)(Hpk + NB);
  _Float16* Alo = Ahi + NB;
  _Float16* Bhi = Alo + NB;
  _Float16* Blo = Bhi + NB;
  int* cnt = (int*)(Blo + NB);         // T*N
  int* off = cnt + kT * kN;            // T*N
  int* cur = off + kT * kN;            // T*N
  int* csr = cur + kT * kN;            // T*E

  hipMemsetAsync(cnt, 0, (size_t)kT * kN * sizeof(int), stream);

  conv_kernel<<<1024, 256, 0, stream>>>(nf, sc_w1, sc_b1, sc_w2, sc_b2, Hpk);
  count_kernel<<<2048, 256, 0, stream>>>(ei, cnt);
  scan_kernel<<<16, 1024, 0, stream>>>(cnt, off, cur);
  place_kernel<<<2048, 256, 0, stream>>>(ei, cur, csr);
  gather_kernel<<<16384, 256, 0, stream>>>(Hpk, csr, off, cnt, Bhi, Blo);
  lstm2_kernel<<<512, 512, 0, stream>>>(Bhi, Blo, Ahi, Alo,
                                        wih0, whh0, bih0, bhh0,
                                        wih1, whh1, bih1, bhh1);
  head_kernel<<<256, 256, 0, stream>>>(Ahi, Alo, win, bin, wout, bout,
                                       pw1, pb1, pw2, pb2, pw3, pb3, out);
}

// Round 12
// 418.824 us; speedup vs baseline: 1.0998x; 1.0290x over previous
//
#include <hip/hip_runtime.h>

// Problem constants
constexpr int kB  = 4;
constexpr int kT  = 16;
constexpr int kN  = 4096;
constexpr int kBN = kB * kN;      // 16384
constexpr int kE  = 32768;
constexpr int kNC = 13;

typedef _Float16 f16x8 __attribute__((ext_vector_type(8)));
typedef _Float16 f16x4 __attribute__((ext_vector_type(4)));
typedef float f32x4 __attribute__((ext_vector_type(4)));

__device__ __forceinline__ float sigm(float x) { return 1.f / (1.f + __expf(-x)); }
__device__ __forceinline__ float tanh_(float x) {
  float e = __expf(2.f * x);
  return 1.f - 2.f / (e + 1.f);
}

__device__ __forceinline__ f32x4 mm3(f16x8 ah, f16x8 al, f16x8 bh, f16x8 bl, f32x4 acc) {
  acc = __builtin_amdgcn_mfma_f32_16x16x32_f16(ah, bh, acc, 0, 0, 0);
  acc = __builtin_amdgcn_mfma_f32_16x16x32_f16(ah, bl, acc, 0, 0, 0);
  acc = __builtin_amdgcn_mfma_f32_16x16x32_f16(al, bh, acc, 0, 0, 0);
  return acc;
}

// split 8 consecutive fp32 into hi/lo fp16 registers
__device__ __forceinline__ void split8(const float* p, f16x8& hi, f16x8& lo) {
  float4 u0 = *(const float4*)p, u1 = *(const float4*)(p + 4);
  float vv[8] = {u0.x, u0.y, u0.z, u0.w, u1.x, u1.y, u1.z, u1.w};
#pragma unroll
  for (int j = 0; j < 8; ++j) {
    _Float16 hj = (_Float16)vv[j];
    hi[j] = hj;
    lo[j] = (_Float16)(vv[j] - (float)hj);
  }
}

// split from transposed LDS activation buffer [col][seq], row stride 68
__device__ __forceinline__ void split8T(const float* base, int kbase, int seq,
                                        f16x8& hi, f16x8& lo) {
  float vv[8];
#pragma unroll
  for (int j = 0; j < 8; ++j) vv[j] = base[(kbase + j) * 68 + seq];
#pragma unroll
  for (int j = 0; j < 8; ++j) {
    _Float16 hj = (_Float16)vv[j];
    hi[j] = hj;
    lo[j] = (_Float16)(vv[j] - (float)hj);
  }
}

// pack fp32 -> (f16 hi | f16 lo << 16)
__device__ __forceinline__ unsigned int packf(float v) {
  _Float16 h = (_Float16)v;
  _Float16 l = (_Float16)(v - (float)h);
  unsigned short uh = __builtin_bit_cast(unsigned short, h);
  unsigned short ul = __builtin_bit_cast(unsigned short, l);
  return (unsigned int)uh | ((unsigned int)ul << 16);
}
// unpack one packed word -> fp32 (hi+lo)
__device__ __forceinline__ float up2(unsigned int w) {
  _Float16 h = __builtin_bit_cast(_Float16, (unsigned short)(w & 0xFFFFu));
  _Float16 l = __builtin_bit_cast(_Float16, (unsigned short)(w >> 16));
  return (float)h + (float)l;
}
// unpack 8 packed words -> hi/lo f16x8 fragments
__device__ __forceinline__ void unpack8(const unsigned int* w, f16x8& hi, f16x8& lo) {
#pragma unroll
  for (int j = 0; j < 8; ++j) {
    hi[j] = __builtin_bit_cast(_Float16, (unsigned short)(w[j] & 0xFFFFu));
    lo[j] = __builtin_bit_cast(_Float16, (unsigned short)(w[j] >> 16));
  }
}

// ---------------------------------------------------------------------------
// Stage 1 v3: per-node MLP (8 -> 64 relu -> 64) as fp16x3 MFMA GEMM.
// ---------------------------------------------------------------------------
__global__ __launch_bounds__(256, 2) void conv_kernel(
    const float* __restrict__ nf, const float* __restrict__ w1,
    const float* __restrict__ b1, const float* __restrict__ w2,
    const float* __restrict__ b2, unsigned int* __restrict__ hpk) {
  __shared__ unsigned int act[256 * 68];   // 69632 B
  int tid = threadIdx.x;
  int w = tid >> 6, lane = tid & 63;
  int q = lane >> 4, i = lane & 15;
  int flat0 = blockIdx.x * 256;            // 256 consecutive (b,t,n) nodes
  int bb = flat0 >> 16;
  int t = (flat0 >> 12) & 15;
  int n0 = flat0 & 4095;

  f16x8 w1h[4], w1l[4];
  f16x8 w2h[4][2], w2l[4][2];
  float bias1[4], bias2[4];
#pragma unroll
  for (int nt = 0; nt < 4; ++nt) {
    int n = nt * 16 + i;
    if (q == 0) split8(w1 + n * 8, w1h[nt], w1l[nt]);
    else { w1h[nt] = (f16x8)0; w1l[nt] = (f16x8)0; }
#pragma unroll
    for (int ks = 0; ks < 2; ++ks)
      split8(w2 + n * 64 + ks * 32 + q * 8, w2h[nt][ks], w2l[nt][ks]);
    bias1[nt] = b1[n];
    bias2[nt] = b2[n];
  }

  // ---- layer 1 ----
  f16x8 xh[4], xl[4];
#pragma unroll
  for (int Mt = 0; Mt < 4; ++Mt) {
    if (q == 0)
      split8(nf + (size_t)(flat0 + w * 64 + Mt * 16 + i) * 8, xh[Mt], xl[Mt]);
    else { xh[Mt] = (f16x8)0; xl[Mt] = (f16x8)0; }
  }
#pragma unroll
  for (int Mt = 0; Mt < 4; ++Mt)
#pragma unroll
    for (int nt = 0; nt < 4; ++nt) {
      f32x4 acc = {bias1[nt], bias1[nt], bias1[nt], bias1[nt]};
      acc = mm3(xh[Mt], xl[Mt], w1h[nt], w1l[nt], acc);
#pragma unroll
      for (int r = 0; r < 4; ++r)
        act[(w * 64 + Mt * 16 + q * 4 + r) * 68 + nt * 16 + i] =
            packf(fmaxf(acc[r], 0.f));
    }
  __syncthreads();

  // ---- layer 2 ----
  f32x4 acc2[4][4];
#pragma unroll
  for (int Mt = 0; Mt < 4; ++Mt)
#pragma unroll
    for (int nt = 0; nt < 4; ++nt) {
      acc2[Mt][nt][0] = bias2[nt]; acc2[Mt][nt][1] = bias2[nt];
      acc2[Mt][nt][2] = bias2[nt]; acc2[Mt][nt][3] = bias2[nt];
    }
#pragma unroll
  for (int ks = 0; ks < 2; ++ks)
#pragma unroll
    for (int Mt = 0; Mt < 4; ++Mt) {
      const unsigned int* p = &act[(w * 64 + Mt * 16 + i) * 68 + ks * 32 + q * 8];
      unsigned int wd[8];
#pragma unroll
      for (int j = 0; j < 4; ++j) {
        uint2 u = *(const uint2*)(p + j * 2);
        wd[2 * j] = u.x; wd[2 * j + 1] = u.y;
      }
      f16x8 ah, al;
      unpack8(wd, ah, al);
#pragma unroll
      for (int nt = 0; nt < 4; ++nt)
        acc2[Mt][nt] = mm3(ah, al, w2h[nt][ks], w2l[nt][ks], acc2[Mt][nt]);
    }
  __syncthreads();   // all act reads done
#pragma unroll
  for (int Mt = 0; Mt < 4; ++Mt)
#pragma unroll
    for (int nt = 0; nt < 4; ++nt)
#pragma unroll
      for (int r = 0; r < 4; ++r)
        act[(w * 64 + Mt * 16 + q * 4 + r) * 68 + nt * 16 + i] =
            packf(acc2[Mt][nt][r]);
  __syncthreads();
  size_t tbase = ((size_t)t * kBN + (size_t)bb * kN + n0) * 64;
#pragma unroll
  for (int k = 0; k < 16; ++k) {
    int d0 = (k * 256 + tid) * 4;
    int node = d0 >> 6, ch = d0 & 63;
    uint2 a = *(const uint2*)&act[node * 68 + ch];
    uint2 b = *(const uint2*)&act[node * 68 + ch + 2];
    uint4 vv = {a.x, a.y, b.x, b.y};
    *(uint4*)(hpk + tbase + d0) = vv;
  }
}

// ---------------------------------------------------------------------------
// Stage 2a: per-(t,dst) edge count (int atomics only)
// ---------------------------------------------------------------------------
__global__ __launch_bounds__(256) void count_kernel(
    const int* __restrict__ ei, int* __restrict__ cnt) {
  int i = blockIdx.x * 256 + threadIdx.x;   // over T*E
  int t = i >> 15, e = i & (kE - 1);
  int dst = ei[t * 2 * kE + kE + e];
  atomicAdd(&cnt[t * kN + dst], 1);
}

// ---------------------------------------------------------------------------
// Stage 2b: per-t exclusive scan over 4096 counts -> offsets + cursor copy.
// ---------------------------------------------------------------------------
__global__ __launch_bounds__(1024) void scan_kernel(
    const int* __restrict__ cnt, int* __restrict__ off, int* __restrict__ cur) {
  __shared__ int sdata[1024];
  int t = blockIdx.x;
  int tid = threadIdx.x;
  const int* c = cnt + t * kN;
  int v0 = c[tid * 4], v1 = c[tid * 4 + 1], v2 = c[tid * 4 + 2], v3 = c[tid * 4 + 3];
  int s = v0 + v1 + v2 + v3;
  sdata[tid] = s;
  __syncthreads();
  for (int d = 1; d < 1024; d <<= 1) {
    int add = (tid >= d) ? sdata[tid - d] : 0;
    __syncthreads();
    sdata[tid] += add;
    __syncthreads();
  }
  int base = sdata[tid] - s;
  int o = t * kN + tid * 4;
  off[o] = base;            cur[o] = base;
  off[o + 1] = base + v0;   cur[o + 1] = base + v0;
  off[o + 2] = base + v0 + v1;        cur[o + 2] = base + v0 + v1;
  off[o + 3] = base + v0 + v1 + v2;   cur[o + 3] = base + v0 + v1 + v2;
}

// ---------------------------------------------------------------------------
// Stage 2c: CSR placement — csr[t*E + pos] = src
// ---------------------------------------------------------------------------
__global__ __launch_bounds__(256) void place_kernel(
    const int* __restrict__ ei, int* __restrict__ cur, int* __restrict__ csr) {
  int i = blockIdx.x * 256 + threadIdx.x;
  int t = i >> 15, e = i & (kE - 1);
  int src = ei[t * 2 * kE + e];
  int dst = ei[t * 2 * kE + kE + e];
  int pos = atomicAdd(&cur[t * kN + dst], 1);
  csr[t * kE + pos] = src;
}

// ---------------------------------------------------------------------------
// Stage 2d: gather + combine, XCD-locality swizzled (R9 WIN: -44 us).
// blockIdx%8 = XCD round-robin pins each t-slice (4 MB of hpk) to one XCD L2.
// Wave per (t,dst); lane = (batch, channel-quad).
// ---------------------------------------------------------------------------
__global__ __launch_bounds__(256) void gather_kernel(
    const unsigned int* __restrict__ hpk, const int* __restrict__ csr,
    const int* __restrict__ off, const int* __restrict__ cnt,
    _Float16* __restrict__ xhi, _Float16* __restrict__ xlo) {
  int blk = blockIdx.x;
  int t = (blk & 7) | ((blk >> 13) << 3);         // xcd-pinned t
  int idx = (blk >> 3) & 1023;
  int d = idx * 4 + (threadIdx.x >> 6);
  int lane = threadIdx.x & 63;
  int b = lane >> 4, cq = lane & 15;              // batch, channel quad
  int o = off[t * kN + d];
  int c = cnt[t * kN + d];
  size_t tb = ((size_t)t * kBN + (size_t)b * kN) * 64 + cq * 4;
  const int* cs = csr + t * kE + o;
  float s[4] = {0.f, 0.f, 0.f, 0.f};
  int j = 0;
  for (; j + 4 <= c; j += 4) {
    int i0 = cs[j], i1 = cs[j + 1], i2 = cs[j + 2], i3 = cs[j + 3];
    uint4 v0 = *(const uint4*)(hpk + tb + (size_t)i0 * 64);
    uint4 v1 = *(const uint4*)(hpk + tb + (size_t)i1 * 64);
    uint4 v2 = *(const uint4*)(hpk + tb + (size_t)i2 * 64);
    uint4 v3 = *(const uint4*)(hpk + tb + (size_t)i3 * 64);
    s[0] += up2(v0.x) + up2(v1.x) + up2(v2.x) + up2(v3.x);
    s[1] += up2(v0.y) + up2(v1.y) + up2(v2.y) + up2(v3.y);
    s[2] += up2(v0.z) + up2(v1.z) + up2(v2.z) + up2(v3.z);
    s[3] += up2(v0.w) + up2(v1.w) + up2(v2.w) + up2(v3.w);
  }
  for (; j < c; ++j) {
    int i0 = cs[j];
    uint4 v0 = *(const uint4*)(hpk + tb + (size_t)i0 * 64);
    s[0] += up2(v0.x); s[1] += up2(v0.y); s[2] += up2(v0.z); s[3] += up2(v0.w);
  }
  uint4 hv = *(const uint4*)(hpk + tb + (size_t)d * 64);
  float hvf[4] = {up2(hv.x), up2(hv.y), up2(hv.z), up2(hv.w)};
  f16x4 ohi, olo;
  float inv = (c > 0) ? 1.f / (float)c : 0.f;
#pragma unroll
  for (int u = 0; u < 4; ++u) {
    float ov = (c > 0) ? (hvf[u] + s[u] * inv) * 0.5f : hvf[u];
    _Float16 hi = (_Float16)ov;
    ohi[u] = hi;
    olo[u] = (_Float16)(ov - (float)hi);
  }
  *(f16x4*)(xhi + tb + (size_t)d * 64) = ohi;
  *(f16x4*)(xlo + tb + (size_t)d * 64) = olo;
}

// ---------------------------------------------------------------------------
// Stage 3 v7: fused 2-layer LSTM, producer-consumer wave specialization,
// SINGLE-PASS grid: 256 blocks x 512 thr (8 waves), 64 seqs/block. Waves 0-3
// = layer 1, waves 4-7 = layer 2, one t apart. Each wave covers 4 M-tiles
// (processed in 2 transient pairs to cap registers). 2x MFMA per barrier
// interval vs R10 amortizes the fixed latency chains. Same 17 barriers.
// Store path unchanged from R8/R10 (scalar gate-section stores — proven).
// LDS = 64 KB (h1f + h2f, double-buffered, 4 M-tiles).
// ---------------------------------------------------------------------------
__global__ __launch_bounds__(512, 2) void lstm2_kernel(
    const _Float16* __restrict__ xhi, const _Float16* __restrict__ xlo,
    _Float16* __restrict__ yhi, _Float16* __restrict__ ylo,
    const float* __restrict__ wih0, const float* __restrict__ whh0,
    const float* __restrict__ bih0, const float* __restrict__ bhh0,
    const float* __restrict__ wih1, const float* __restrict__ whh1,
    const float* __restrict__ bih1, const float* __restrict__ bhh1) {
  __shared__ _Float16 h1f[2][4][2][2][512];  // [buf][Mt][ks][hl][lane*8+j] 32KB
  __shared__ _Float16 h2f[2][4][2][2][512];  // 32KB
  int tid = threadIdx.x;
  int grp = tid >> 8;                  // 0 = layer 1, 1 = layer 2
  int cb = (tid >> 6) & 3, lane = tid & 63;
  int q = lane >> 4, i = lane & 15;
  int s0 = blockIdx.x * 64;

  const float* Wih = grp ? wih1 : wih0;
  const float* Whh = grp ? whh1 : whh0;
  const float* Bih = grp ? bih1 : bih0;
  const float* Bhh = grp ? bhh1 : bhh0;

  // weights -> registers, B-frag order (hi/lo split)
  f16x8 wr[2][4][2][2];   // [mat][g][ks][hl]
#pragma unroll
  for (int mat = 0; mat < 2; ++mat) {
    const float* W = mat ? Whh : Wih;
#pragma unroll
    for (int g = 0; g < 4; ++g) {
      int row = (g * 4 + cb) * 16 + i;
#pragma unroll
      for (int ks = 0; ks < 2; ++ks)
        split8(W + row * 64 + ks * 32 + q * 8, wr[mat][g][ks][0], wr[mat][g][ks][1]);
    }
  }
  int ch = cb * 16 + i;
  float bias4[4];
#pragma unroll
  for (int g = 0; g < 4; ++g) bias4[g] = Bih[g * 64 + ch] + Bhh[g * 64 + ch];
  float cst[4][4];
#pragma unroll
  for (int Mt = 0; Mt < 4; ++Mt)
#pragma unroll
    for (int r = 0; r < 4; ++r) cst[Mt][r] = 0.f;
  int ks2 = ch >> 5, q2 = (ch >> 3) & 3, j2 = ch & 7;
  int p = 0;

  for (int it = 0; it < kT + 1; ++it) {
    if (grp == 0) {
      // ---------------- layer 1, t = it ----------------
      if (it < kT) {
        int t = it;
#pragma unroll
        for (int mp = 0; mp < 2; ++mp) {     // Mt pair: {2mp, 2mp+1}
          f32x4 acc[2][4];
#pragma unroll
          for (int ml = 0; ml < 2; ++ml)
#pragma unroll
            for (int g = 0; g < 4; ++g) {
              acc[ml][g][0] = bias4[g]; acc[ml][g][1] = bias4[g];
              acc[ml][g][2] = bias4[g]; acc[ml][g][3] = bias4[g];
            }
          // x contribution from global
#pragma unroll
          for (int ks = 0; ks < 2; ++ks) {
            f16x8 xah[2], xal[2];
#pragma unroll
            for (int ml = 0; ml < 2; ++ml) {
              size_t base = ((size_t)t * kBN + s0 + (2 * mp + ml) * 16 + i) * 64 + ks * 32 + q * 8;
              xah[ml] = *(const f16x8*)(xhi + base);
              xal[ml] = *(const f16x8*)(xlo + base);
            }
#pragma unroll
            for (int g = 0; g < 4; ++g)
#pragma unroll
              for (int ml = 0; ml < 2; ++ml)
                acc[ml][g] = mm3(xah[ml], xal[ml], wr[0][g][ks][0], wr[0][g][ks][1], acc[ml][g]);
          }
          // recurrent contribution
          if (t > 0) {
#pragma unroll
            for (int ks = 0; ks < 2; ++ks) {
              f16x8 hah[2], hal[2];
#pragma unroll
              for (int ml = 0; ml < 2; ++ml) {
                hah[ml] = *(const f16x8*)&h1f[p][2 * mp + ml][ks][0][lane * 8];
                hal[ml] = *(const f16x8*)&h1f[p][2 * mp + ml][ks][1][lane * 8];
              }
#pragma unroll
              for (int g = 0; g < 4; ++g)
#pragma unroll
                for (int ml = 0; ml < 2; ++ml)
                  acc[ml][g] = mm3(hah[ml], hal[ml], wr[1][g][ks][0], wr[1][g][ks][1], acc[ml][g]);
            }
          }
          // gates -> h1(t) -> LDS frags only
#pragma unroll
          for (int ml = 0; ml < 2; ++ml) {
            int Mt = 2 * mp + ml;
#pragma unroll
            for (int r = 0; r < 4; ++r) {
              float zi = acc[ml][0][r], zf = acc[ml][1][r];
              float zg = acc[ml][2][r], zo = acc[ml][3][r];
              float ig = sigm(zi), fg = sigm(zf), gg = tanh_(zg), og = sigm(zo);
              float c = fg * cst[Mt][r] + ig * gg;
              cst[Mt][r] = c;
              float hv = og * tanh_(c);
              int row = q * 4 + r;
              _Float16 hh = (_Float16)hv;
              _Float16 hl = (_Float16)(hv - (float)hh);
              int lane2 = q2 * 16 + row;
              h1f[p ^ 1][Mt][ks2][0][lane2 * 8 + j2] = hh;
              h1f[p ^ 1][Mt][ks2][1][lane2 * 8 + j2] = hl;
            }
          }
        }
      }
    } else {
      // ---------------- layer 2, t = it - 1 ----------------
      if (it >= 1) {
        int t = it - 1;
#pragma unroll
        for (int mp = 0; mp < 2; ++mp) {
          f32x4 acc[2][4];
#pragma unroll
          for (int ml = 0; ml < 2; ++ml)
#pragma unroll
            for (int g = 0; g < 4; ++g) {
              acc[ml][g][0] = bias4[g]; acc[ml][g][1] = bias4[g];
              acc[ml][g][2] = bias4[g]; acc[ml][g][3] = bias4[g];
            }
          // input contribution: h1(t) from LDS (A-frag layout already)
#pragma unroll
          for (int ks = 0; ks < 2; ++ks) {
            f16x8 xah[2], xal[2];
#pragma unroll
            for (int ml = 0; ml < 2; ++ml) {
              xah[ml] = *(const f16x8*)&h1f[p][2 * mp + ml][ks][0][lane * 8];
              xal[ml] = *(const f16x8*)&h1f[p][2 * mp + ml][ks][1][lane * 8];
            }
#pragma unroll
            for (int g = 0; g < 4; ++g)
#pragma unroll
              for (int ml = 0; ml < 2; ++ml)
                acc[ml][g] = mm3(xah[ml], xal[ml], wr[0][g][ks][0], wr[0][g][ks][1], acc[ml][g]);
          }
          // recurrent contribution
          if (t > 0) {
#pragma unroll
            for (int ks = 0; ks < 2; ++ks) {
              f16x8 hah[2], hal[2];
#pragma unroll
              for (int ml = 0; ml < 2; ++ml) {
                hah[ml] = *(const f16x8*)&h2f[p][2 * mp + ml][ks][0][lane * 8];
                hal[ml] = *(const f16x8*)&h2f[p][2 * mp + ml][ks][1][lane * 8];
              }
#pragma unroll
              for (int g = 0; g < 4; ++g)
#pragma unroll
                for (int ml = 0; ml < 2; ++ml)
                  acc[ml][g] = mm3(hah[ml], hal[ml], wr[1][g][ks][0], wr[1][g][ks][1], acc[ml][g]);
            }
          }
          // gates -> h2(t) -> global y + LDS frags
#pragma unroll
          for (int ml = 0; ml < 2; ++ml) {
            int Mt = 2 * mp + ml;
#pragma unroll
            for (int r = 0; r < 4; ++r) {
              float zi = acc[ml][0][r], zf = acc[ml][1][r];
              float zg = acc[ml][2][r], zo = acc[ml][3][r];
              float ig = sigm(zi), fg = sigm(zf), gg = tanh_(zg), og = sigm(zo);
              float c = fg * cst[Mt][r] + ig * gg;
              cst[Mt][r] = c;
              float hv = og * tanh_(c);
              int row = q * 4 + r;
              size_t ob = ((size_t)t * kBN + s0 + Mt * 16 + row) * 64 + ch;
              _Float16 hh = (_Float16)hv;
              _Float16 hl = (_Float16)(hv - (float)hh);
              yhi[ob] = hh;
              ylo[ob] = hl;
              int lane2 = q2 * 16 + row;
              h2f[p ^ 1][Mt][ks2][0][lane2 * 8 + j2] = hh;
              h2f[p ^ 1][Mt][ks2][1][lane2 * 8 + j2] = hl;
            }
          }
        }
      }
    }
    __syncthreads();
    p ^= 1;
  }
}

// ---------------------------------------------------------------------------
// Weight-fragment stagers for the head (B-frag order, fp16 hi/lo).
// ---------------------------------------------------------------------------
__device__ __forceinline__ void stage_frags64(const float* W, _Float16* base,
                                              int O, int tid) {
  int total = O * 16;
  for (int idx = tid; idx < total; idx += 256) {
    int r = idx >> 4, k4 = idx & 15;
    float4 v = *(const float4*)&W[r * 64 + k4 * 4];
    int k = k4 * 4;
    int nt = r >> 4, ii = r & 15, ks = k >> 5, qq = (k >> 3) & 3, j0 = k & 7;
    _Float16* dh = base + ((nt * 2 + ks) * 2) * 512 + (qq * 16 + ii) * 8 + j0;
    _Float16* dl = dh + 512;
    float vv[4] = {v.x, v.y, v.z, v.w};
#pragma unroll
    for (int u = 0; u < 4; ++u) {
      _Float16 hh = (_Float16)vv[u];
      dh[u] = hh;
      dl[u] = (_Float16)(vv[u] - (float)hh);
    }
  }
}

__device__ __forceinline__ void stage_frags128(const float* W, _Float16* base,
                                               int O, int tid) {
  int total = O * 32;
  for (int idx = tid; idx < total; idx += 256) {
    int r = idx >> 5, k4 = idx & 31;
    float4 v = *(const float4*)&W[r * 128 + k4 * 4];
    int k = k4 * 4;
    int nt = r >> 4, ii = r & 15, ks = k >> 5, qq = (k >> 3) & 3, j0 = k & 7;
    _Float16* dh = base + ((nt * 4 + ks) * 2) * 512 + (qq * 16 + ii) * 8 + j0;
    _Float16* dl = dh + 512;
    float vv[4] = {v.x, v.y, v.z, v.w};
#pragma unroll
    for (int u = 0; u < 4; ++u) {
      _Float16 hh = (_Float16)vv[u];
      dh[u] = hh;
      dl[u] = (_Float16)(vv[u] - (float)hh);
    }
  }
}

// ---------------------------------------------------------------------------
// Stage 4 v3: fused attention + head MLP, fp16x3 MFMA; x input is f16 hi/lo.
// ---------------------------------------------------------------------------
__global__ __launch_bounds__(256, 1) void head_kernel(
    const _Float16* __restrict__ xhi, const _Float16* __restrict__ xlo,
    const float* __restrict__ win, const float* __restrict__ bin,
    const float* __restrict__ wout, const float* __restrict__ bout,
    const float* __restrict__ pw1, const float* __restrict__ pb1,
    const float* __restrict__ pw2, const float* __restrict__ pb2,
    const float* __restrict__ pw3, const float* __restrict__ pb3,
    float* __restrict__ out) {
  __shared__ __align__(16) float smem[30720];   // 120 KB
  _Float16* wb = (_Float16*)smem;               // 84 KB weight frags
  float* buf = smem + 21504;                    // 36 KB activations

  int tid = threadIdx.x;
  int w = tid >> 6, lane = tid & 63;
  int q = lane >> 4, i = lane & 15;
  int s0 = blockIdx.x * 64;

  stage_frags64(win, wb, 64, tid);                 // Wq
  stage_frags64(win + 64 * 64, wb + 8192, 128, tid);  // Wkv
  __syncthreads();

  // ---- q projection at t=15 ----
  {
    f16x8 ah[2], al[2];
#pragma unroll
    for (int ks = 0; ks < 2; ++ks) {
      size_t base = ((size_t)15 * kBN + s0 + w * 16 + i) * 64 + ks * 32 + q * 8;
      ah[ks] = *(const f16x8*)(xhi + base);
      al[ks] = *(const f16x8*)(xlo + base);
    }
#pragma unroll
    for (int nt = 0; nt < 4; ++nt) {
      float bias = bin[nt * 16 + i];
      f32x4 acc = {bias, bias, bias, bias};
#pragma unroll
      for (int ks = 0; ks < 2; ++ks) {
        const _Float16* bp = wb + ((nt * 2 + ks) * 2) * 512 + lane * 8;
        acc = mm3(ah[ks], al[ks], *(const f16x8*)bp, *(const f16x8*)(bp + 512), acc);
      }
      *(float4*)&buf[(nt * 16 + i) * 68 + w * 16 + q * 4] = *(float4*)&acc;
    }
  }
  __syncthreads();
  float qreg[16];
#pragma unroll
  for (int d = 0; d < 16; ++d) qreg[d] = buf[(w * 16 + d) * 68 + lane];
  __syncthreads();

  // ---- t loop: kv projection via MFMA + online-softmax attention ----
  float m = -1e30f, l = 0.f;
  float o[16];
#pragma unroll
  for (int d = 0; d < 16; ++d) o[d] = 0.f;

  for (int t = 0; t < kT; ++t) {
    f16x8 xah[4][2], xal[4][2];
#pragma unroll
    for (int Mt = 0; Mt < 4; ++Mt)
#pragma unroll
      for (int ks = 0; ks < 2; ++ks) {
        size_t base = ((size_t)t * kBN + s0 + Mt * 16 + i) * 64 + ks * 32 + q * 8;
        xah[Mt][ks] = *(const f16x8*)(xhi + base);
        xal[Mt][ks] = *(const f16x8*)(xlo + base);
      }
#pragma unroll
    for (int u = 0; u < 2; ++u) {
      int nt = 2 * w + u;                    // cols 0..63 = k, 64..127 = v
      float bias = bin[64 + nt * 16 + i];
      f16x8 bh[2], bl[2];
#pragma unroll
      for (int ks = 0; ks < 2; ++ks) {
        const _Float16* bp = wb + 8192 + ((nt * 2 + ks) * 2) * 512 + lane * 8;
        bh[ks] = *(const f16x8*)bp;
        bl[ks] = *(const f16x8*)(bp + 512);
      }
#pragma unroll
      for (int Mt = 0; Mt < 4; ++Mt) {
        f32x4 acc = {bias, bias, bias, bias};
#pragma unroll
        for (int ks = 0; ks < 2; ++ks)
          acc = mm3(xah[Mt][ks], xal[Mt][ks], bh[ks], bl[ks], acc);
        *(float4*)&buf[(nt * 16 + i) * 68 + Mt * 16 + q * 4] = *(float4*)&acc;
      }
    }
    __syncthreads();
    float sc = 0.f;
#pragma unroll
    for (int d = 0; d < 16; ++d) sc += qreg[d] * buf[(w * 16 + d) * 68 + lane];
    sc *= 0.25f;   // 1/sqrt(HD=16)
    float mn = fmaxf(m, sc);
    float alpha = __expf(m - mn);
    float pp = __expf(sc - mn);
    l = l * alpha + pp;
#pragma unroll
    for (int d = 0; d < 16; ++d)
      o[d] = o[d] * alpha + pp * buf[(64 + w * 16 + d) * 68 + lane];
    m = mn;
    __syncthreads();
  }

  // ---- write normalized o (transposed, cols 0..63) ----
  float linv = 1.f / l;
#pragma unroll
  for (int d = 0; d < 16; ++d) buf[(w * 16 + d) * 68 + lane] = o[d] * linv;
  __syncthreads();

  // ---- restage phase-B weights ----
  stage_frags64(wout, wb, 64, tid);
  stage_frags64(pw1, wb + 8192, 128, tid);
  stage_frags128(pw2, wb + 24576, 64, tid);
  for (int idx = tid; idx < 256; idx += 256) {   // pw3 padded to 16 rows
    int r = idx >> 4, k4 = idx & 15;
    float4 v = {0.f, 0.f, 0.f, 0.f};
    if (r < kNC) v = *(const float4*)&pw3[r * 64 + k4 * 4];
    int k = k4 * 4;
    int ks = k >> 5, qq = (k >> 3) & 3, j0 = k & 7;
    _Float16* dh = wb + 40960 + (ks * 2) * 512 + (qq * 16 + r) * 8 + j0;
    _Float16* dl = dh + 512;
    float vv[4] = {v.x, v.y, v.z, v.w};
#pragma unroll
    for (int u = 0; u < 4; ++u) {
      _Float16 hh = (_Float16)vv[u];
      dh[u] = hh;
      dl[u] = (_Float16)(vv[u] - (float)hh);
    }
  }
  __syncthreads();

  int seq = w * 16 + i;

  // ---- out projection ----
  {
    f16x8 ah[2], al[2];
    split8T(buf, q * 8, seq, ah[0], al[0]);
    split8T(buf, 32 + q * 8, seq, ah[1], al[1]);
#pragma unroll
    for (int nt = 0; nt < 4; ++nt) {
      float bias = bout[nt * 16 + i];
      f32x4 acc = {bias, bias, bias, bias};
#pragma unroll
      for (int ks = 0; ks < 2; ++ks) {
        const _Float16* bp = wb + ((nt * 2 + ks) * 2) * 512 + lane * 8;
        acc = mm3(ah[ks], al[ks], *(const f16x8*)bp, *(const f16x8*)(bp + 512), acc);
      }
      *(float4*)&buf[4352 + (nt * 16 + i) * 68 + w * 16 + q * 4] = *(float4*)&acc;
    }
  }
  __syncthreads();

  // ---- z1 = relu(fin @ pw1^T + pb1) ----
  {
    f16x8 ah[2], al[2];
    split8T(buf + 4352, q * 8, seq, ah[0], al[0]);
    split8T(buf + 4352, 32 + q * 8, seq, ah[1], al[1]);
    __syncthreads();
#pragma unroll
    for (int nt = 0; nt < 8; ++nt) {
      float bias = pb1[nt * 16 + i];
      f32x4 acc = {bias, bias, bias, bias};
#pragma unroll
      for (int ks = 0; ks < 2; ++ks) {
        const _Float16* bp = wb + 8192 + ((nt * 2 + ks) * 2) * 512 + lane * 8;
        acc = mm3(ah[ks], al[ks], *(const f16x8*)bp, *(const f16x8*)(bp + 512), acc);
      }
      f32x4 r4;
#pragma unroll
      for (int r = 0; r < 4; ++r) r4[r] = fmaxf(acc[r], 0.f);
      *(float4*)&buf[(nt * 16 + i) * 68 + w * 16 + q * 4] = *(float4*)&r4;
    }
  }
  __syncthreads();

  // ---- z2 = relu(z1 @ pw2^T + pb2) ----
  {
    f16x8 ah[4], al[4];
#pragma unroll
    for (int ks = 0; ks < 4; ++ks)
      split8T(buf, ks * 32 + q * 8, seq, ah[ks], al[ks]);
    __syncthreads();
#pragma unroll
    for (int nt = 0; nt < 4; ++nt) {
      float bias = pb2[nt * 16 + i];
      f32x4 acc = {bias, bias, bias, bias};
#pragma unroll
      for (int ks = 0; ks < 4; ++ks) {
        const _Float16* bp = wb + 24576 + ((nt * 4 + ks) * 2) * 512 + lane * 8;
        acc = mm3(ah[ks], al[ks], *(const f16x8*)bp, *(const f16x8*)(bp + 512), acc);
      }
      f32x4 r4;
#pragma unroll
      for (int r = 0; r < 4; ++r) r4[r] = fmaxf(acc[r], 0.f);
      *(float4*)&buf[(nt * 16 + i) * 68 + w * 16 + q * 4] = *(float4*)&r4;
    }
  }
  __syncthreads();

  // ---- logits ----
  {
    f16x8 ah[2], al[2];
    split8T(buf, q * 8, seq, ah[0], al[0]);
    split8T(buf, 32 + q * 8, seq, ah[1], al[1]);
    f32x4 acc = {0.f, 0.f, 0.f, 0.f};
#pragma unroll
    for (int ks = 0; ks < 2; ++ks) {
      const _Float16* bp = wb + 40960 + (ks * 2) * 512 + lane * 8;
      acc = mm3(ah[ks], al[ks], *(const f16x8*)bp, *(const f16x8*)(bp + 512), acc);
    }
    if (i < kNC) {
      float bb = pb3[i];
#pragma unroll
      for (int r = 0; r < 4; ++r)
        out[(size_t)(s0 + w * 16 + q * 4 + r) * kNC + i] = acc[r] + bb;
    }
  }
}

// ---------------------------------------------------------------------------
extern "C" void kernel_launch(void* const* d_in, const int* in_sizes, int n_in,
                              void* d_out, int out_size, void* d_ws, size_t ws_size,
                              hipStream_t stream) {
  const float* nf    = (const float*)d_in[0];
  const int*   ei    = (const int*)d_in[1];
  const float* sc_w1 = (const float*)d_in[2];
  const float* sc_b1 = (const float*)d_in[3];
  const float* sc_w2 = (const float*)d_in[4];
  const float* sc_b2 = (const float*)d_in[5];
  const float* wih0  = (const float*)d_in[6];
  const float* whh0  = (const float*)d_in[7];
  const float* bih0  = (const float*)d_in[8];
  const float* bhh0  = (const float*)d_in[9];
  const float* wih1  = (const float*)d_in[10];
  const float* whh1  = (const float*)d_in[11];
  const float* bih1  = (const float*)d_in[12];
  const float* bhh1  = (const float*)d_in[13];
  const float* win   = (const float*)d_in[14];
  const float* bin   = (const float*)d_in[15];
  const float* wout  = (const float*)d_in[16];
  const float* bout  = (const float*)d_in[17];
  const float* pw1   = (const float*)d_in[18];
  const float* pb1   = (const float*)d_in[19];
  const float* pw2   = (const float*)d_in[20];
  const float* pb2   = (const float*)d_in[21];
  const float* pw3   = (const float*)d_in[22];
  const float* pb3   = (const float*)d_in[23];
  float* out = (float*)d_out;

  const size_t NB = (size_t)kT * kBN * 64;  // 16,777,216 elements per buffer
  unsigned int* Hpk = (unsigned int*)d_ws;  // packed conv output (NB uints)
  _Float16* Ahi = (_Float16*)(Hpk + NB);
  _Float16* Alo = Ahi + NB;
  _Float16* Bhi = Alo + NB;
  _Float16* Blo = Bhi + NB;
  int* cnt = (int*)(Blo + NB);         // T*N
  int* off = cnt + kT * kN;            // T*N
  int* cur = off + kT * kN;            // T*N
  int* csr = cur + kT * kN;            // T*E

  hipMemsetAsync(cnt, 0, (size_t)kT * kN * sizeof(int), stream);

  conv_kernel<<<1024, 256, 0, stream>>>(nf, sc_w1, sc_b1, sc_w2, sc_b2, Hpk);
  count_kernel<<<2048, 256, 0, stream>>>(ei, cnt);
  scan_kernel<<<16, 1024, 0, stream>>>(cnt, off, cur);
  place_kernel<<<2048, 256, 0, stream>>>(ei, cur, csr);
  gather_kernel<<<16384, 256, 0, stream>>>(Hpk, csr, off, cnt, Bhi, Blo);
  lstm2_kernel<<<256, 512, 0, stream>>>(Bhi, Blo, Ahi, Alo,
                                        wih0, whh0, bih0, bhh0,
                                        wih1, whh1, bih1, bhh1);
  head_kernel<<<256, 256, 0, stream>>>(Ahi, Alo, win, bin, wout, bout,
                                       pw1, pb1, pw2, pb2, pw3, pb3, out);
}